// Round 11
// baseline (350.338 us; speedup 1.0000x reference)
//
#include <hip/hip_runtime.h>

// ---------------------------------------------------------------------------
// GraphSAGE forward: 3x SAGEConv(mean) + ReLU(1,2) + final 128->2 projection.
// Activations carried as bf16 hi/lo pairs (split-bf16 3-term MFMA numerics).
// GEMM: NO LDS, NO barriers — A and B fragments both loaded direct to
// registers in MFMA layout, double-buffered one K-step ahead (L2/L3 latency
// hides under the 48-MFMA phase; 4x intra-block A duplication is L2-absorbed).
// Layer3+out-proj collapsed to [256][4] Wc; tu fused into GEMM-2 epilogue.
// ---------------------------------------------------------------------------

constexpr int D_IN  = 128;
constexpr int D_HID = 256;

typedef __attribute__((ext_vector_type(8))) short short8x;
typedef __attribute__((ext_vector_type(4))) float f32x4;

// ---------------- CSR build ----------------

__global__ void count_deg_kernel(const int* __restrict__ dst, int* __restrict__ cnt, int E) {
    int stride = gridDim.x * blockDim.x;
    for (int i = blockIdx.x * blockDim.x + threadIdx.x; i < E; i += stride)
        atomicAdd(&cnt[dst[i]], 1);
}

__global__ __launch_bounds__(1024) void scan_local_kernel(
    const int* __restrict__ cnt, int* __restrict__ row_ptr,
    int* __restrict__ bsums, int Nn) {
    __shared__ int wsum[16];
    const int tid = threadIdx.x, lane = tid & 63, wid = tid >> 6;
    const int idx0 = blockIdx.x * 4096 + tid * 4;
    int v[4];
    #pragma unroll
    for (int j = 0; j < 4; ++j) {
        int idx = idx0 + j;
        v[j] = (idx < Nn) ? cnt[idx] : 0;
    }
    int s = v[0] + v[1] + v[2] + v[3];
    int xi = s;
    #pragma unroll
    for (int o = 1; o < 64; o <<= 1) {
        int t = __shfl_up(xi, o, 64);
        if (lane >= o) xi += t;
    }
    if (lane == 63) wsum[wid] = xi;
    __syncthreads();
    if (wid == 0) {
        int t = (lane < 16) ? wsum[lane] : 0;
        #pragma unroll
        for (int o = 1; o < 16; o <<= 1) {
            int u = __shfl_up(t, o, 64);
            if (lane >= o) t += u;
        }
        if (lane < 16) wsum[lane] = t;
    }
    __syncthreads();
    int off = (wid ? wsum[wid - 1] : 0) + xi - s;
    int run = off;
    #pragma unroll
    for (int j = 0; j < 4; ++j) {
        int idx = idx0 + j;
        if (idx <= Nn) row_ptr[idx] = run;
        run += v[j];
    }
    if (tid == 0) bsums[blockIdx.x] = wsum[15];
}

__global__ void scan_bsums_kernel(int* __restrict__ bsums, int nb) {
    int lane = threadIdx.x & 63;
    int v = (lane < nb) ? bsums[lane] : 0;
    int xi = v;
    #pragma unroll
    for (int o = 1; o < 64; o <<= 1) {
        int t = __shfl_up(xi, o, 64);
        if (lane >= o) xi += t;
    }
    if (lane < nb) bsums[lane] = xi - v;  // exclusive
}

__global__ __launch_bounds__(1024) void scan_add_kernel(
    int* __restrict__ row_ptr, const int* __restrict__ bsums, int Nn) {
    const int b = blockIdx.x;
    const int base = bsums[b];
    const int idx0 = b * 4096 + threadIdx.x * 4;
    #pragma unroll
    for (int j = 0; j < 4; ++j) {
        int idx = idx0 + j;
        if (idx <= Nn) row_ptr[idx] += base;
    }
}

__global__ void scatter_kernel(const int* __restrict__ src, const int* __restrict__ dst,
                               const int* __restrict__ row_ptr, int* __restrict__ cursor,
                               int* __restrict__ esrc, int E) {
    int stride = gridDim.x * blockDim.x;
    for (int i = blockIdx.x * blockDim.x + threadIdx.x; i < E; i += stride) {
        int d = dst[i];
        int p = atomicAdd(&cursor[d], 1);
        esrc[row_ptr[d] + p] = src[i];
    }
}

// ---------------- bf16 split helpers ----------------

__device__ inline unsigned bf16_rne(float f) {
    unsigned u = __float_as_uint(f);
    return (u + 0x7fffu + ((u >> 16) & 1u)) >> 16;
}

__device__ inline void split_pair(float v, unsigned& h, unsigned& l) {
    h = bf16_rne(v);
    float hf = __uint_as_float(h << 16);
    l = bf16_rne(v - hf);
}

// ---------------- fp32 -> bf16 hi/lo pair convert ----------------

__global__ __launch_bounds__(256) void f32_pair_kernel(
    const float* __restrict__ in, unsigned short* __restrict__ oh,
    unsigned short* __restrict__ ol, int n8) {
    int stride = gridDim.x * blockDim.x;
    for (int i = blockIdx.x * blockDim.x + threadIdx.x; i < n8; i += stride) {
        const float4* p = (const float4*)(in + (size_t)i * 8);
        float4 v0 = p[0], v1 = p[1];
        float f[8] = {v0.x, v0.y, v0.z, v0.w, v1.x, v1.y, v1.z, v1.w};
        unsigned h[8], l[8];
        #pragma unroll
        for (int j = 0; j < 8; ++j) split_pair(f[j], h[j], l[j]);
        uint4 qh, ql;
        qh.x = h[0] | (h[1] << 16); qh.y = h[2] | (h[3] << 16);
        qh.z = h[4] | (h[5] << 16); qh.w = h[6] | (h[7] << 16);
        ql.x = l[0] | (l[1] << 16); ql.y = l[2] | (l[3] << 16);
        ql.z = l[4] | (l[5] << 16); ql.w = l[6] | (l[7] << 16);
        *(uint4*)(oh + (size_t)i * 8) = qh;
        *(uint4*)(ol + (size_t)i * 8) = ql;
    }
}

// ---------------- weight prep: fragment-linear hi/lo bf16 ----------------
// WTh[(((n16*KS32 + k32)*64 + lane)*8 + e], n = n16*16+(lane&15),
// k = k32*32 + (lane>>4)*8 + e.

__global__ void prep_wt_kernel(const float* __restrict__ Wl, const float* __restrict__ Wr,
                               int K1, int K2, int Nc,
                               short* __restrict__ WTh, short* __restrict__ WTl) {
    const int KE = K1 + K2;
    const int KSTEPS = KE / 32;
    const int total = Nc * KE;
    int i = blockIdx.x * blockDim.x + threadIdx.x;
    if (i >= total) return;
    int e = i & 7;
    int t = i >> 3;
    int l = t & 63;
    int t2 = t >> 6;
    int k32 = t2 % KSTEPS;
    int n16 = t2 / KSTEPS;
    int n = n16 * 16 + (l & 15);
    int k = k32 * 32 + (l >> 4) * 8 + e;
    float w = (k < K1) ? Wl[(size_t)k * Nc + n] : Wr[(size_t)(k - K1) * Nc + n];
    unsigned h, lo;
    split_pair(w, h, lo);
    WTh[i] = (short)h;
    WTl[i] = (short)lo;
}

// ---------------- fused layer3+out weights: Wc[256][4], bc[2] ----------------

__global__ __launch_bounds__(1024) void prep_wc_kernel(
    const float* __restrict__ Wl3, const float* __restrict__ Wr3,
    const float* __restrict__ b3, const float* __restrict__ Wout,
    const float* __restrict__ bout, float* __restrict__ Wc, float* __restrict__ bc) {
    int tid = threadIdx.x;         // h = tid>>2 in [0,256), c = tid&3
    int h = tid >> 2, c = tid & 3;
    const float* Ws = (c < 2) ? Wl3 : Wr3;
    int o = c & 1;
    float s = 0.f;
    for (int e = 0; e < 128; ++e) s += Ws[h * 128 + e] * Wout[e * 2 + o];
    Wc[h * 4 + c] = s;
    if (tid < 2) {
        float sb = 0.f;
        for (int e = 0; e < 128; ++e) sb += b3[e] * Wout[e * 2 + tid];
        bc[tid] = sb + bout[tid];
    }
}

// ---------------- mean aggregation over bf16 rows -> hi/lo pair ------------

__device__ inline void addbf8(const uint4& q, float* a) {
    a[0] += __uint_as_float(q.x << 16); a[1] += __uint_as_float(q.x & 0xFFFF0000u);
    a[2] += __uint_as_float(q.y << 16); a[3] += __uint_as_float(q.y & 0xFFFF0000u);
    a[4] += __uint_as_float(q.z << 16); a[5] += __uint_as_float(q.z & 0xFFFF0000u);
    a[6] += __uint_as_float(q.w << 16); a[7] += __uint_as_float(q.w & 0xFFFF0000u);
}

template <int D>
__global__ __launch_bounds__(256) void aggregate_pair_kernel(
    const unsigned short* __restrict__ xb, const int* __restrict__ row_ptr,
    const int* __restrict__ esrc, unsigned short* __restrict__ aggh,
    unsigned short* __restrict__ aggl, int Nn) {
    constexpr int LPN = D / 8;
    constexpr int NPW = 64 / LPN;
    const int lane = threadIdx.x & 63;
    const int sub = lane / LPN;
    const int sl = lane % LPN;
    const int wave = (blockIdx.x * blockDim.x + threadIdx.x) >> 6;
    const int nw = (gridDim.x * blockDim.x) >> 6;
    for (int base = wave * NPW; base < Nn; base += nw * NPW) {
        int node = base + sub;
        if (node >= Nn) continue;
        int beg = row_ptr[node], end = row_ptr[node + 1];
        float a0[8] = {}, a1[8] = {}, a2[8] = {}, a3[8] = {};
        int e = beg;
        for (; e + 4 <= end; e += 4) {
            int s0 = esrc[e], s1 = esrc[e + 1], s2 = esrc[e + 2], s3 = esrc[e + 3];
            uint4 q0 = *(const uint4*)(xb + (size_t)s0 * D + sl * 8);
            uint4 q1 = *(const uint4*)(xb + (size_t)s1 * D + sl * 8);
            uint4 q2 = *(const uint4*)(xb + (size_t)s2 * D + sl * 8);
            uint4 q3 = *(const uint4*)(xb + (size_t)s3 * D + sl * 8);
            addbf8(q0, a0); addbf8(q1, a1); addbf8(q2, a2); addbf8(q3, a3);
        }
        for (; e < end; ++e) {
            int s0 = esrc[e];
            uint4 q0 = *(const uint4*)(xb + (size_t)s0 * D + sl * 8);
            addbf8(q0, a0);
        }
        float inv = 1.0f / fmaxf((float)(end - beg), 1.0f);
        unsigned h[8], l[8];
        #pragma unroll
        for (int i = 0; i < 8; ++i)
            split_pair((a0[i] + a1[i] + a2[i] + a3[i]) * inv, h[i], l[i]);
        uint4 qh, ql;
        qh.x = h[0] | (h[1] << 16); qh.y = h[2] | (h[3] << 16);
        qh.z = h[4] | (h[5] << 16); qh.w = h[6] | (h[7] << 16);
        ql.x = l[0] | (l[1] << 16); ql.y = l[2] | (l[3] << 16);
        ql.z = l[4] | (l[5] << 16); ql.w = l[6] | (l[7] << 16);
        *(uint4*)(aggh + (size_t)node * D + sl * 8) = qh;
        *(uint4*)(aggl + (size_t)node * D + sl * 8) = ql;
    }
}

// ---------------- register-pipelined split-bf16 MFMA GEMM ----------------
// C = act([A1|A2] @ Wcat + b). A pre-split bf16 pairs, row-major [M][K].
// Block: 64 rows x 256 cols, 4 waves (wave wc owns cols wc*64..+63).
// NO LDS, NO barriers: A frags (row = m*16+(lane&15), k-chunk = lane>>4) and
// B frags (fragment-linear W) loaded direct to registers, double-buffered one
// K-step ahead. Intra-block 4x A duplication is L2-absorbed.

template <int K1, int K2, int N, bool RELU, bool TU>
__global__ __launch_bounds__(256, 2) void gemm_reg_kernel(
    const unsigned short* __restrict__ A1h, const unsigned short* __restrict__ A1l,
    const unsigned short* __restrict__ A2h, const unsigned short* __restrict__ A2l,
    const short8x* __restrict__ WTh, const short8x* __restrict__ WTl,
    const float* __restrict__ bias,
    unsigned short* __restrict__ Ch, unsigned short* __restrict__ Cl,
    const float* __restrict__ Wc, const float* __restrict__ bc,
    float* __restrict__ tuout, int M) {
    constexpr int KSTEPS = (K1 + K2) / 32;
    __shared__ float4 sRed[4][64];                 // TU epilogue only (4 KB)
    const int tid = threadIdx.x, lane = tid & 63, wc = tid >> 6;
    const int bm = blockIdx.x * 64;
    const int kc = (lane >> 4) * 8;

    unsigned ro1[4], ro2[4];
    #pragma unroll
    for (int m = 0; m < 4; ++m) {
        int g = bm + m * 16 + (lane & 15);
        if (g >= M) g = M - 1;
        ro1[m] = (unsigned)g * K1;
        ro2[m] = (unsigned)g * K2;
    }

    auto loadA = [&](int ks, short8x* ah, short8x* al) {
        const int k0 = ks * 32;
        if (k0 < K1) {
            #pragma unroll
            for (int m = 0; m < 4; ++m) {
                ah[m] = *(const short8x*)(A1h + ro1[m] + k0 + kc);
                al[m] = *(const short8x*)(A1l + ro1[m] + k0 + kc);
            }
        } else {
            #pragma unroll
            for (int m = 0; m < 4; ++m) {
                ah[m] = *(const short8x*)(A2h + ro2[m] + (k0 - K1) + kc);
                al[m] = *(const short8x*)(A2l + ro2[m] + (k0 - K1) + kc);
            }
        }
    };

    auto loadB = [&](int ks, short8x* bh, short8x* bl) {
        #pragma unroll
        for (int n = 0; n < 4; ++n) {
            size_t widx = ((size_t)(wc * 4 + n) * KSTEPS + ks) * 64 + lane;
            bh[n] = WTh[widx];
            bl[n] = WTl[widx];
        }
    };

    f32x4 acc[4][4];
    #pragma unroll
    for (int m = 0; m < 4; ++m)
        #pragma unroll
        for (int n = 0; n < 4; ++n)
            acc[m][n] = (f32x4){0.f, 0.f, 0.f, 0.f};

    short8x ahC[4], alC[4], bhC[4], blC[4];
    short8x ahN[4], alN[4], bhN[4], blN[4];
    loadA(0, ahC, alC);
    loadB(0, bhC, blC);

    #pragma unroll
    for (int ks = 0; ks < KSTEPS; ++ks) {
        if (ks + 1 < KSTEPS) {
            loadA(ks + 1, ahN, alN);     // issue next step's 16 loads early;
            loadB(ks + 1, bhN, blN);     // latency hides under this step's MFMAs
        }
        #pragma unroll
        for (int m = 0; m < 4; ++m)
            #pragma unroll
            for (int n = 0; n < 4; ++n) {
                acc[m][n] = __builtin_amdgcn_mfma_f32_16x16x32_bf16(ahC[m], bhC[n], acc[m][n], 0, 0, 0);
                acc[m][n] = __builtin_amdgcn_mfma_f32_16x16x32_bf16(ahC[m], blC[n], acc[m][n], 0, 0, 0);
                acc[m][n] = __builtin_amdgcn_mfma_f32_16x16x32_bf16(alC[m], bhC[n], acc[m][n], 0, 0, 0);
            }
        if (ks + 1 < KSTEPS) {
            #pragma unroll
            for (int i = 0; i < 4; ++i) {   // renamed away by full unroll
                ahC[i] = ahN[i]; alC[i] = alN[i];
                bhC[i] = bhN[i]; blC[i] = blN[i];
            }
        }
    }

    float bv[4];
    #pragma unroll
    for (int n = 0; n < 4; ++n) bv[n] = bias[wc * 64 + n * 16 + (lane & 15)];

    if constexpr (!TU) {
        #pragma unroll
        for (int n = 0; n < 4; ++n) {
            const int col = wc * 64 + n * 16 + (lane & 15);
            #pragma unroll
            for (int m = 0; m < 4; ++m) {
                #pragma unroll
                for (int j = 0; j < 4; ++j) {
                    int row = bm + m * 16 + (lane >> 4) * 4 + j;
                    if (row < M) {
                        float v = acc[m][n][j] + bv[n];
                        if (RELU) v = fmaxf(v, 0.f);
                        unsigned h, l;
                        split_pair(v, h, l);
                        Ch[(size_t)row * N + col] = (unsigned short)h;
                        Cl[(size_t)row * N + col] = (unsigned short)l;
                    }
                }
            }
        }
    } else {
        float4 wcv[4];
        #pragma unroll
        for (int n = 0; n < 4; ++n)
            wcv[n] = *(const float4*)(Wc + (size_t)(wc * 64 + n * 16 + (lane & 15)) * 4);
        #pragma unroll
        for (int m = 0; m < 4; ++m) {
            #pragma unroll
            for (int j = 0; j < 4; ++j) {
                float4 p = make_float4(0.f, 0.f, 0.f, 0.f);
                #pragma unroll
                for (int n = 0; n < 4; ++n) {
                    float v = acc[m][n][j] + bv[n];
                    if (RELU) v = fmaxf(v, 0.f);
                    p.x += v * wcv[n].x; p.y += v * wcv[n].y;
                    p.z += v * wcv[n].z; p.w += v * wcv[n].w;
                }
                #pragma unroll
                for (int mk = 8; mk >= 1; mk >>= 1) {
                    p.x += __shfl_xor(p.x, mk, 64);
                    p.y += __shfl_xor(p.y, mk, 64);
                    p.z += __shfl_xor(p.z, mk, 64);
                    p.w += __shfl_xor(p.w, mk, 64);
                }
                if ((lane & 15) == 0)
                    sRed[wc][m * 16 + (lane >> 4) * 4 + j] = p;
            }
        }
        __syncthreads();
        if (tid < 64) {
            int row = bm + tid;
            float4 a = sRed[0][tid], b2 = sRed[1][tid], c2 = sRed[2][tid], d2 = sRed[3][tid];
            float4 t;
            t.x = a.x + b2.x + c2.x + d2.x;
            t.y = a.y + b2.y + c2.y + d2.y;
            t.z = a.z + b2.z + c2.z + d2.z + bc[0];
            t.w = a.w + b2.w + c2.w + d2.w + bc[1];
            if (row < M) *(float4*)(tuout + (size_t)row * 4) = t;
        }
    }
}

// ---------------- out_i = mean_j t_j + u_i  (D=2 gather, L2-resident) ------

__global__ __launch_bounds__(256) void final_out_kernel(
    const float* __restrict__ tu, const int* __restrict__ row_ptr,
    const int* __restrict__ esrc, float* __restrict__ out, int Nn) {
    int stride = gridDim.x * blockDim.x;
    for (int i = blockIdx.x * blockDim.x + threadIdx.x; i < Nn; i += stride) {
        int beg = row_ptr[i], end = row_ptr[i + 1];
        float s0 = 0.f, s1 = 0.f;
        for (int e = beg; e < end; ++e) {
            int s = esrc[e];
            float2 tv = *(const float2*)(tu + (size_t)s * 4);
            s0 += tv.x; s1 += tv.y;
        }
        float inv = 1.0f / fmaxf((float)(end - beg), 1.0f);
        float u0 = tu[(size_t)i * 4 + 2], u1 = tu[(size_t)i * 4 + 3];
        *(float2*)(out + (size_t)i * 2) = make_float2(s0 * inv + u0, s1 * inv + u1);
    }
}

// ---------------- launch ----------------

extern "C" void kernel_launch(void* const* d_in, const int* in_sizes, int n_in,
                              void* d_out, int out_size, void* d_ws, size_t ws_size,
                              hipStream_t stream) {
    const float* x    = (const float*)d_in[0];
    const int*   ei   = (const int*)d_in[1];
    const float* Wl1  = (const float*)d_in[2];
    const float* Wr1  = (const float*)d_in[3];
    const float* b1   = (const float*)d_in[4];
    const float* Wl2  = (const float*)d_in[5];
    const float* Wr2  = (const float*)d_in[6];
    const float* b2   = (const float*)d_in[7];
    const float* Wl3  = (const float*)d_in[8];
    const float* Wr3  = (const float*)d_in[9];
    const float* b3   = (const float*)d_in[10];
    const float* Wout = (const float*)d_in[11];
    const float* bout = (const float*)d_in[12];

    const int Nn = in_sizes[0] / D_IN;     // 50000
    const int E  = in_sizes[1] / 2;        // 600000

    char* ws = (char*)d_ws;
    size_t off = 0;
    auto alloc = [&](size_t b) { size_t o = off; off = (off + b + 255) & ~(size_t)255; return o; };

    unsigned short* xh    = (unsigned short*)(ws + alloc((size_t)Nn * D_IN * 2));
    unsigned short* xl    = (unsigned short*)(ws + alloc((size_t)Nn * D_IN * 2));
    unsigned short* agg1h = (unsigned short*)(ws + alloc((size_t)Nn * D_IN * 2));
    unsigned short* agg1l = (unsigned short*)(ws + alloc((size_t)Nn * D_IN * 2));
    int*   row_ptr = (int*)(ws + alloc((size_t)(Nn + 1) * 4));
    int*   cnt     = (int*)(ws + alloc((size_t)Nn * 4));
    int*   cursor  = (int*)(ws + alloc((size_t)Nn * 4));
    int*   bsums   = (int*)(ws + alloc((size_t)256 * 4));
    int*   esrc    = (int*)(ws + alloc((size_t)E * 4));
    unsigned short* hAh   = (unsigned short*)(ws + alloc((size_t)Nn * D_HID * 2));
    unsigned short* hAl   = (unsigned short*)(ws + alloc((size_t)Nn * D_HID * 2));
    unsigned short* agg2h = (unsigned short*)(ws + alloc((size_t)Nn * D_HID * 2));
    unsigned short* agg2l = (unsigned short*)(ws + alloc((size_t)Nn * D_HID * 2));
    float* tu      = (float*)(ws + alloc((size_t)Nn * 4 * 4));
    float* Wc      = (float*)(ws + alloc((size_t)256 * 4 * 4));
    float* bc      = (float*)(ws + alloc((size_t)2 * 4));
    short* wt1h    = (short*)(ws + alloc((size_t)256 * 256 * 2));
    short* wt1l    = (short*)(ws + alloc((size_t)256 * 256 * 2));
    short* wt2h    = (short*)(ws + alloc((size_t)256 * 512 * 2));
    short* wt2l    = (short*)(ws + alloc((size_t)256 * 512 * 2));

    const int* src = ei;
    const int* dst = ei + E;

    hipMemsetAsync(cnt, 0, (size_t)Nn * 4, stream);
    hipMemsetAsync(cursor, 0, (size_t)Nn * 4, stream);

    prep_wt_kernel<<<(256 * 256 + 255) / 256, 256, 0, stream>>>(Wl1, Wr1, 128, 128, 256, wt1h, wt1l);
    prep_wt_kernel<<<(256 * 512 + 255) / 256, 256, 0, stream>>>(Wl2, Wr2, 256, 256, 256, wt2h, wt2l);
    prep_wc_kernel<<<1, 1024, 0, stream>>>(Wl3, Wr3, b3, Wout, bout, Wc, bc);
    f32_pair_kernel<<<2048, 256, 0, stream>>>(x, xh, xl, Nn * D_IN / 8);

    count_deg_kernel<<<2048, 256, 0, stream>>>(dst, cnt, E);
    const int nb = (Nn + 1 + 4095) / 4096;   // 13
    scan_local_kernel<<<nb, 1024, 0, stream>>>(cnt, row_ptr, bsums, Nn);
    scan_bsums_kernel<<<1, 64, 0, stream>>>(bsums, nb);
    scan_add_kernel<<<nb, 1024, 0, stream>>>(row_ptr, bsums, Nn);
    scatter_kernel<<<2048, 256, 0, stream>>>(src, dst, row_ptr, cursor, esrc, E);

    const int gm64 = (Nn + 63) / 64;    // 782

    // Layer 1: [agg1 | x] -> 256, relu; emits hi/lo bf16 pair
    aggregate_pair_kernel<128><<<2048, 256, 0, stream>>>(xh, row_ptr, esrc, agg1h, agg1l, Nn);
    gemm_reg_kernel<128, 128, 256, true, false>
        <<<gm64, 256, 0, stream>>>(agg1h, agg1l, xh, xl,
                                   (const short8x*)wt1h, (const short8x*)wt1l,
                                   b1, hAh, hAl, nullptr, nullptr, nullptr, Nn);

    // Layer 2: [agg2 | h1] -> 256, relu; fused tu epilogue (no h2 materialized)
    aggregate_pair_kernel<256><<<2048, 256, 0, stream>>>(hAh, row_ptr, esrc, agg2h, agg2l, Nn);
    gemm_reg_kernel<256, 256, 256, true, true>
        <<<gm64, 256, 0, stream>>>(agg2h, agg2l, hAh, hAl,
                                   (const short8x*)wt2h, (const short8x*)wt2l,
                                   b2, nullptr, nullptr, Wc, bc, tu, Nn);

    // out = mean-gather(t) + u
    final_out_kernel<<<512, 256, 0, stream>>>(tu, row_ptr, esrc, (float*)d_out, Nn);
}

// Round 12
// 270.748 us; speedup vs baseline: 1.2940x; 1.2940x over previous
//
#include <hip/hip_runtime.h>

// ---------------------------------------------------------------------------
// GraphSAGE forward: 3x SAGEConv(mean) + ReLU(1,2) + final 128->2 projection.
// Activations carried as bf16 hi/lo pairs (split-bf16 3-term MFMA numerics).
// GEMM (round-10 proven template, BK widened to 128): double-buffered LDS A
// (four 32-k sub-steps per barrier), XOR-swizzled via pre-swizzled
// global_load_lds source; fragment-linear W reg-prefetched one sub-step
// ahead; one __syncthreads per K-step (~930cy MFMA cover vs ~900cy HBM).
// Layer3+out-proj collapsed to [256][4] Wc; tu fused into GEMM-2 epilogue.
// Setup (weight prep + x convert + degree count) fused into one kernel.
// ---------------------------------------------------------------------------

constexpr int D_IN  = 128;
constexpr int D_HID = 256;

typedef __attribute__((ext_vector_type(8))) short short8x;
typedef __attribute__((ext_vector_type(4))) float f32x4;

// ---------------- bf16 split helpers ----------------

__device__ inline unsigned bf16_rne(float f) {
    unsigned u = __float_as_uint(f);
    return (u + 0x7fffu + ((u >> 16) & 1u)) >> 16;
}

__device__ inline void split_pair(float v, unsigned& h, unsigned& l) {
    h = bf16_rne(v);
    float hf = __uint_as_float(h << 16);
    l = bf16_rne(v - hf);
}

// ---------------- fused setup: prep_wt x2, prep_wc, f32->pair(x), count_deg --

__device__ inline void prep_wt_elem(const float* __restrict__ Wl,
                                    const float* __restrict__ Wr,
                                    int K1, int K2, int Nc, int i,
                                    short* __restrict__ WTh, short* __restrict__ WTl) {
    const int KE = K1 + K2;
    const int KSTEPS = KE / 32;
    int e = i & 7;
    int t = i >> 3;
    int l = t & 63;
    int t2 = t >> 6;
    int k32 = t2 % KSTEPS;
    int n16 = t2 / KSTEPS;
    int n = n16 * 16 + (l & 15);
    int k = k32 * 32 + (l >> 4) * 8 + e;
    float w = (k < K1) ? Wl[(size_t)k * Nc + n] : Wr[(size_t)(k - K1) * Nc + n];
    unsigned h, lo;
    split_pair(w, h, lo);
    WTh[i] = (short)h;
    WTl[i] = (short)lo;
}

__global__ __launch_bounds__(256) void setup_kernel(
    const float* __restrict__ Wl1, const float* __restrict__ Wr1,
    short* __restrict__ wt1h, short* __restrict__ wt1l,
    const float* __restrict__ Wl2, const float* __restrict__ Wr2,
    short* __restrict__ wt2h, short* __restrict__ wt2l,
    const float* __restrict__ Wl3, const float* __restrict__ Wr3,
    const float* __restrict__ b3, const float* __restrict__ Wout,
    const float* __restrict__ bout, float* __restrict__ Wc, float* __restrict__ bc,
    const float* __restrict__ x, unsigned short* __restrict__ xh,
    unsigned short* __restrict__ xl,
    const int* __restrict__ dst, int* __restrict__ cnt,
    int Nn, int E) {
    const int gtid = blockIdx.x * blockDim.x + threadIdx.x;
    const int gs = gridDim.x * blockDim.x;

    // x -> bf16 hi/lo pairs (8 floats per item)
    const int n8 = Nn * D_IN / 8;
    for (int i = gtid; i < n8; i += gs) {
        const float4* p = (const float4*)(x + (size_t)i * 8);
        float4 v0 = p[0], v1 = p[1];
        float f[8] = {v0.x, v0.y, v0.z, v0.w, v1.x, v1.y, v1.z, v1.w};
        unsigned h[8], l[8];
        #pragma unroll
        for (int j = 0; j < 8; ++j) split_pair(f[j], h[j], l[j]);
        uint4 qh, ql;
        qh.x = h[0] | (h[1] << 16); qh.y = h[2] | (h[3] << 16);
        qh.z = h[4] | (h[5] << 16); qh.w = h[6] | (h[7] << 16);
        ql.x = l[0] | (l[1] << 16); ql.y = l[2] | (l[3] << 16);
        ql.z = l[4] | (l[5] << 16); ql.w = l[6] | (l[7] << 16);
        *(uint4*)(xh + (size_t)i * 8) = qh;
        *(uint4*)(xl + (size_t)i * 8) = ql;
    }

    // degree count
    for (int i = gtid; i < E; i += gs)
        atomicAdd(&cnt[dst[i]], 1);

    // weight prep (fragment-linear hi/lo)
    for (int i = gtid; i < 256 * 256; i += gs)
        prep_wt_elem(Wl1, Wr1, 128, 128, 256, i, wt1h, wt1l);
    for (int i = gtid; i < 256 * 512; i += gs)
        prep_wt_elem(Wl2, Wr2, 256, 256, 256, i, wt2h, wt2l);

    // fused layer3+out weights
    for (int i = gtid; i < 1024; i += gs) {
        int hh = i >> 2, c = i & 3;
        const float* Ws = (c < 2) ? Wl3 : Wr3;
        int o = c & 1;
        float s = 0.f;
        for (int e = 0; e < 128; ++e) s += Ws[hh * 128 + e] * Wout[e * 2 + o];
        Wc[hh * 4 + c] = s;
    }
    if (gtid < 2) {
        float sb = 0.f;
        for (int e = 0; e < 128; ++e) sb += b3[e] * Wout[e * 2 + gtid];
        bc[gtid] = sb + bout[gtid];
    }
}

// ---------------- CSR scan + scatter ----------------

__global__ __launch_bounds__(1024) void scan_local_kernel(
    const int* __restrict__ cnt, int* __restrict__ row_ptr,
    int* __restrict__ bsums, int Nn) {
    __shared__ int wsum[16];
    const int tid = threadIdx.x, lane = tid & 63, wid = tid >> 6;
    const int idx0 = blockIdx.x * 4096 + tid * 4;
    int v[4];
    #pragma unroll
    for (int j = 0; j < 4; ++j) {
        int idx = idx0 + j;
        v[j] = (idx < Nn) ? cnt[idx] : 0;
    }
    int s = v[0] + v[1] + v[2] + v[3];
    int xi = s;
    #pragma unroll
    for (int o = 1; o < 64; o <<= 1) {
        int t = __shfl_up(xi, o, 64);
        if (lane >= o) xi += t;
    }
    if (lane == 63) wsum[wid] = xi;
    __syncthreads();
    if (wid == 0) {
        int t = (lane < 16) ? wsum[lane] : 0;
        #pragma unroll
        for (int o = 1; o < 16; o <<= 1) {
            int u = __shfl_up(t, o, 64);
            if (lane >= o) t += u;
        }
        if (lane < 16) wsum[lane] = t;
    }
    __syncthreads();
    int off = (wid ? wsum[wid - 1] : 0) + xi - s;
    int run = off;
    #pragma unroll
    for (int j = 0; j < 4; ++j) {
        int idx = idx0 + j;
        if (idx <= Nn) row_ptr[idx] = run;
        run += v[j];
    }
    if (tid == 0) bsums[blockIdx.x] = wsum[15];
}

__global__ void scan_bsums_kernel(int* __restrict__ bsums, int nb) {
    int lane = threadIdx.x & 63;
    int v = (lane < nb) ? bsums[lane] : 0;
    int xi = v;
    #pragma unroll
    for (int o = 1; o < 64; o <<= 1) {
        int t = __shfl_up(xi, o, 64);
        if (lane >= o) xi += t;
    }
    if (lane < nb) bsums[lane] = xi - v;  // exclusive
}

__global__ __launch_bounds__(1024) void scan_add_kernel(
    int* __restrict__ row_ptr, const int* __restrict__ bsums, int Nn) {
    const int b = blockIdx.x;
    const int base = bsums[b];
    const int idx0 = b * 4096 + threadIdx.x * 4;
    #pragma unroll
    for (int j = 0; j < 4; ++j) {
        int idx = idx0 + j;
        if (idx <= Nn) row_ptr[idx] += base;
    }
}

__global__ void scatter_kernel(const int* __restrict__ src, const int* __restrict__ dst,
                               const int* __restrict__ row_ptr, int* __restrict__ cursor,
                               int* __restrict__ esrc, int E) {
    int stride = gridDim.x * blockDim.x;
    for (int i = blockIdx.x * blockDim.x + threadIdx.x; i < E; i += stride) {
        int d = dst[i];
        int p = atomicAdd(&cursor[d], 1);
        esrc[row_ptr[d] + p] = src[i];
    }
}

// ---------------- mean aggregation over bf16 rows -> hi/lo pair ------------

__device__ inline void addbf8(const uint4& q, float* a) {
    a[0] += __uint_as_float(q.x << 16); a[1] += __uint_as_float(q.x & 0xFFFF0000u);
    a[2] += __uint_as_float(q.y << 16); a[3] += __uint_as_float(q.y & 0xFFFF0000u);
    a[4] += __uint_as_float(q.z << 16); a[5] += __uint_as_float(q.z & 0xFFFF0000u);
    a[6] += __uint_as_float(q.w << 16); a[7] += __uint_as_float(q.w & 0xFFFF0000u);
}

template <int D>
__global__ __launch_bounds__(256) void aggregate_pair_kernel(
    const unsigned short* __restrict__ xb, const int* __restrict__ row_ptr,
    const int* __restrict__ esrc, unsigned short* __restrict__ aggh,
    unsigned short* __restrict__ aggl, int Nn) {
    constexpr int LPN = D / 8;
    constexpr int NPW = 64 / LPN;
    const int lane = threadIdx.x & 63;
    const int sub = lane / LPN;
    const int sl = lane % LPN;
    const int wave = (blockIdx.x * blockDim.x + threadIdx.x) >> 6;
    const int nw = (gridDim.x * blockDim.x) >> 6;
    for (int base = wave * NPW; base < Nn; base += nw * NPW) {
        int node = base + sub;
        if (node >= Nn) continue;
        int beg = row_ptr[node], end = row_ptr[node + 1];
        float a0[8] = {}, a1[8] = {}, a2[8] = {}, a3[8] = {};
        int e = beg;
        for (; e + 4 <= end; e += 4) {
            int s0 = esrc[e], s1 = esrc[e + 1], s2 = esrc[e + 2], s3 = esrc[e + 3];
            uint4 q0 = *(const uint4*)(xb + (size_t)s0 * D + sl * 8);
            uint4 q1 = *(const uint4*)(xb + (size_t)s1 * D + sl * 8);
            uint4 q2 = *(const uint4*)(xb + (size_t)s2 * D + sl * 8);
            uint4 q3 = *(const uint4*)(xb + (size_t)s3 * D + sl * 8);
            addbf8(q0, a0); addbf8(q1, a1); addbf8(q2, a2); addbf8(q3, a3);
        }
        for (; e < end; ++e) {
            int s0 = esrc[e];
            uint4 q0 = *(const uint4*)(xb + (size_t)s0 * D + sl * 8);
            addbf8(q0, a0);
        }
        float inv = 1.0f / fmaxf((float)(end - beg), 1.0f);
        unsigned h[8], l[8];
        #pragma unroll
        for (int i = 0; i < 8; ++i)
            split_pair((a0[i] + a1[i] + a2[i] + a3[i]) * inv, h[i], l[i]);
        uint4 qh, ql;
        qh.x = h[0] | (h[1] << 16); qh.y = h[2] | (h[3] << 16);
        qh.z = h[4] | (h[5] << 16); qh.w = h[6] | (h[7] << 16);
        ql.x = l[0] | (l[1] << 16); ql.y = l[2] | (l[3] << 16);
        ql.z = l[4] | (l[5] << 16); ql.w = l[6] | (l[7] << 16);
        *(uint4*)(aggh + (size_t)node * D + sl * 8) = qh;
        *(uint4*)(aggl + (size_t)node * D + sl * 8) = ql;
    }
}

// ---------------- LDS-staged split-bf16 MFMA GEMM, BK=128 ----------------
// C = act([A1|A2] @ Wcat + b). A pre-split bf16 pairs in global.
// Block: 64 rows x 256 cols, 4 waves (wave wc owns cols wc*64..+63).
// sA[2][64][256] shorts: row = 512B = 32 chunks of 16B; chunks 0-15 = Ah
// (k = chunk*8), 16-31 = Al; chunks XOR-swizzled by row&7 within 8-groups
// via pre-swizzled global_load_lds SOURCE (LDS dest linear).
// Per K-step: 4 x {8 ds_read + 48 MFMA} (~930cy) covers the HBM A-stage
// (~900cy); B for sub-step s+1 reg-prefetched under sub-step s's MFMAs.
// One __syncthreads per step (round-10 proven sync; no counted vmcnt).

template <int K1, int K2, int N, bool RELU, bool TU>
__global__ __launch_bounds__(256, 2) void gemm_lds_kernel(
    const unsigned short* __restrict__ A1h, const unsigned short* __restrict__ A1l,
    const unsigned short* __restrict__ A2h, const unsigned short* __restrict__ A2l,
    const short8x* __restrict__ WTh, const short8x* __restrict__ WTl,
    const float* __restrict__ bias,
    unsigned short* __restrict__ Ch, unsigned short* __restrict__ Cl,
    const float* __restrict__ Wc, const float* __restrict__ bc,
    float* __restrict__ tuout, int M) {
    constexpr int KEFF = K1 + K2;
    constexpr int KS128 = KEFF / 128;
    constexpr int KS32 = KEFF / 32;
    __shared__ __attribute__((aligned(16))) unsigned short sA[2][64][256]; // 64 KB
    float4* sRed = (float4*)&sA[0][0][0];   // overlay: used only after K-loop
    const int tid = threadIdx.x, lane = tid & 63, wc = tid >> 6;
    const int bm = blockIdx.x * 64;

    // stage one BK=128 A-tile (Ah+Al, 32 KB) into sA[buf]; 8 gload_lds/thread.
    auto stage = [&](int buf, int ks) {
        int k0 = ks * 128;
        const unsigned short *Hb, *Lb; int kloc, Kx;
        if (k0 < K1) { Hb = A1h; Lb = A1l; kloc = k0;      Kx = K1; }
        else         { Hb = A2h; Lb = A2l; kloc = k0 - K1; Kx = K2; }
        #pragma unroll
        for (int q = 0; q < 8; ++q) {
            int r0 = wc * 16 + q * 2;                 // wave-uniform base row
            int rloc = r0 + (lane >> 5);
            int grow = bm + rloc; if (grow >= M) grow = M - 1;
            int p = lane & 31;                        // dest chunk position
            int c = ((p & 7) ^ (rloc & 7)) | (p & 24);// logical chunk at p
            const unsigned short* base = (c & 16) ? Lb : Hb;
            const unsigned short* g = base + (size_t)grow * Kx + kloc + (c & 15) * 8;
            __builtin_amdgcn_global_load_lds((const unsigned*)g,
                                             (unsigned*)&sA[buf][r0][0], 16, 0, 0);
        }
    };

    auto loadB = [&](int ks32, short8x* bh, short8x* bl) {
        #pragma unroll
        for (int n = 0; n < 4; ++n) {
            size_t widx = ((size_t)(wc * 4 + n) * KS32 + ks32) * 64 + lane;
            bh[n] = WTh[widx];
            bl[n] = WTl[widx];
        }
    };

    f32x4 acc[4][4];
    #pragma unroll
    for (int m = 0; m < 4; ++m)
        #pragma unroll
        for (int n = 0; n < 4; ++n)
            acc[m][n] = (f32x4){0.f, 0.f, 0.f, 0.f};

    short8x bhC[4], blC[4], bhN[4], blN[4];
    stage(0, 0);
    loadB(0, bhC, blC);
    __syncthreads();

    #pragma unroll
    for (int ks = 0; ks < KS128; ++ks) {
        const int cur = ks & 1;
        if (ks + 1 < KS128) stage(cur ^ 1, ks + 1);   // prefetch next A-tile

        #pragma unroll
        for (int s = 0; s < 4; ++s) {
            const int nxt = ks * 4 + s + 1;
            if (nxt < KS32) loadB(nxt, bhN, blN);     // B one sub-step ahead

            short8x ah[4], al[4];
            #pragma unroll
            for (int m = 0; m < 4; ++m) {
                const unsigned short* rp = &sA[cur][m * 16 + (lane & 15)][0];
                int c = s * 4 + (lane >> 4);                    // 0..15
                int p = ((c & 7) ^ (lane & 7)) | (c & 8);       // row&7==lane&7
                ah[m] = *(const short8x*)(rp + p * 8);
                al[m] = *(const short8x*)(rp + p * 8 + 128);    // +16 chunks
            }

            #pragma unroll
            for (int m = 0; m < 4; ++m)
                #pragma unroll
                for (int n = 0; n < 4; ++n) {
                    acc[m][n] = __builtin_amdgcn_mfma_f32_16x16x32_bf16(ah[m], bhC[n], acc[m][n], 0, 0, 0);
                    acc[m][n] = __builtin_amdgcn_mfma_f32_16x16x32_bf16(ah[m], blC[n], acc[m][n], 0, 0, 0);
                    acc[m][n] = __builtin_amdgcn_mfma_f32_16x16x32_bf16(al[m], bhC[n], acc[m][n], 0, 0, 0);
                }
            if (nxt < KS32) {
                #pragma unroll
                for (int n = 0; n < 4; ++n) {   // renamed away by full unroll
                    bhC[n] = bhN[n];
                    blC[n] = blN[n];
                }
            }
        }
        __syncthreads();   // drains A-stage + B prefetch before buffer swap
    }

    float bv[4];
    #pragma unroll
    for (int n = 0; n < 4; ++n) bv[n] = bias[wc * 64 + n * 16 + (lane & 15)];

    if constexpr (!TU) {
        #pragma unroll
        for (int n = 0; n < 4; ++n) {
            const int col = wc * 64 + n * 16 + (lane & 15);
            #pragma unroll
            for (int m = 0; m < 4; ++m) {
                #pragma unroll
                for (int j = 0; j < 4; ++j) {
                    int row = bm + m * 16 + (lane >> 4) * 4 + j;
                    if (row < M) {
                        float v = acc[m][n][j] + bv[n];
                        if (RELU) v = fmaxf(v, 0.f);
                        unsigned h, l;
                        split_pair(v, h, l);
                        Ch[(size_t)row * N + col] = (unsigned short)h;
                        Cl[(size_t)row * N + col] = (unsigned short)l;
                    }
                }
            }
        }
    } else {
        float4 wcv[4];
        #pragma unroll
        for (int n = 0; n < 4; ++n)
            wcv[n] = *(const float4*)(Wc + (size_t)(wc * 64 + n * 16 + (lane & 15)) * 4);
        #pragma unroll
        for (int m = 0; m < 4; ++m) {
            #pragma unroll
            for (int j = 0; j < 4; ++j) {
                float4 p = make_float4(0.f, 0.f, 0.f, 0.f);
                #pragma unroll
                for (int n = 0; n < 4; ++n) {
                    float v = acc[m][n][j] + bv[n];
                    if (RELU) v = fmaxf(v, 0.f);
                    p.x += v * wcv[n].x; p.y += v * wcv[n].y;
                    p.z += v * wcv[n].z; p.w += v * wcv[n].w;
                }
                #pragma unroll
                for (int mk = 8; mk >= 1; mk >>= 1) {
                    p.x += __shfl_xor(p.x, mk, 64);
                    p.y += __shfl_xor(p.y, mk, 64);
                    p.z += __shfl_xor(p.z, mk, 64);
                    p.w += __shfl_xor(p.w, mk, 64);
                }
                if ((lane & 15) == 0)
                    sRed[wc * 64 + m * 16 + (lane >> 4) * 4 + j] = p;
            }
        }
        __syncthreads();
        if (tid < 64) {
            int row = bm + tid;
            float4 a = sRed[0 * 64 + tid], b2 = sRed[1 * 64 + tid];
            float4 c2 = sRed[2 * 64 + tid], d2 = sRed[3 * 64 + tid];
            float4 t;
            t.x = a.x + b2.x + c2.x + d2.x;
            t.y = a.y + b2.y + c2.y + d2.y;
            t.z = a.z + b2.z + c2.z + d2.z + bc[0];
            t.w = a.w + b2.w + c2.w + d2.w + bc[1];
            if (row < M) *(float4*)(tuout + (size_t)row * 4) = t;
        }
    }
}

// ---------------- out_i = mean_j t_j + u_i  (D=2 gather, L2-resident) ------

__global__ __launch_bounds__(256) void final_out_kernel(
    const float* __restrict__ tu, const int* __restrict__ row_ptr,
    const int* __restrict__ esrc, float* __restrict__ out, int Nn) {
    int stride = gridDim.x * blockDim.x;
    for (int i = blockIdx.x * blockDim.x + threadIdx.x; i < Nn; i += stride) {
        int beg = row_ptr[i], end = row_ptr[i + 1];
        float s0 = 0.f, s1 = 0.f;
        for (int e = beg; e < end; ++e) {
            int s = esrc[e];
            float2 tv = *(const float2*)(tu + (size_t)s * 4);
            s0 += tv.x; s1 += tv.y;
        }
        float inv = 1.0f / fmaxf((float)(end - beg), 1.0f);
        float u0 = tu[(size_t)i * 4 + 2], u1 = tu[(size_t)i * 4 + 3];
        *(float2*)(out + (size_t)i * 2) = make_float2(s0 * inv + u0, s1 * inv + u1);
    }
}

// ---------------- launch ----------------

extern "C" void kernel_launch(void* const* d_in, const int* in_sizes, int n_in,
                              void* d_out, int out_size, void* d_ws, size_t ws_size,
                              hipStream_t stream) {
    const float* x    = (const float*)d_in[0];
    const int*   ei   = (const int*)d_in[1];
    const float* Wl1  = (const float*)d_in[2];
    const float* Wr1  = (const float*)d_in[3];
    const float* b1   = (const float*)d_in[4];
    const float* Wl2  = (const float*)d_in[5];
    const float* Wr2  = (const float*)d_in[6];
    const float* b2   = (const float*)d_in[7];
    const float* Wl3  = (const float*)d_in[8];
    const float* Wr3  = (const float*)d_in[9];
    const float* b3   = (const float*)d_in[10];
    const float* Wout = (const float*)d_in[11];
    const float* bout = (const float*)d_in[12];

    const int Nn = in_sizes[0] / D_IN;     // 50000
    const int E  = in_sizes[1] / 2;        // 600000

    char* ws = (char*)d_ws;
    size_t off = 0;
    auto alloc = [&](size_t b) { size_t o = off; off = (off + b + 255) & ~(size_t)255; return o; };

    unsigned short* xh    = (unsigned short*)(ws + alloc((size_t)Nn * D_IN * 2));
    unsigned short* xl    = (unsigned short*)(ws + alloc((size_t)Nn * D_IN * 2));
    unsigned short* agg1h = (unsigned short*)(ws + alloc((size_t)Nn * D_IN * 2));
    unsigned short* agg1l = (unsigned short*)(ws + alloc((size_t)Nn * D_IN * 2));
    int*   row_ptr = (int*)(ws + alloc((size_t)(Nn + 1) * 4));
    int*   cnt     = (int*)(ws + alloc((size_t)Nn * 4));
    int*   cursor  = (int*)(ws + alloc((size_t)Nn * 4));
    int*   bsums   = (int*)(ws + alloc((size_t)256 * 4));
    int*   esrc    = (int*)(ws + alloc((size_t)E * 4));
    unsigned short* hAh   = (unsigned short*)(ws + alloc((size_t)Nn * D_HID * 2));
    unsigned short* hAl   = (unsigned short*)(ws + alloc((size_t)Nn * D_HID * 2));
    unsigned short* agg2h = (unsigned short*)(ws + alloc((size_t)Nn * D_HID * 2));
    unsigned short* agg2l = (unsigned short*)(ws + alloc((size_t)Nn * D_HID * 2));
    float* tu      = (float*)(ws + alloc((size_t)Nn * 4 * 4));
    float* Wc      = (float*)(ws + alloc((size_t)256 * 4 * 4));
    float* bc      = (float*)(ws + alloc((size_t)2 * 4));
    short* wt1h    = (short*)(ws + alloc((size_t)256 * 256 * 2));
    short* wt1l    = (short*)(ws + alloc((size_t)256 * 256 * 2));
    short* wt2h    = (short*)(ws + alloc((size_t)256 * 512 * 2));
    short* wt2l    = (short*)(ws + alloc((size_t)256 * 512 * 2));

    const int* src = ei;
    const int* dst = ei + E;

    hipMemsetAsync(cnt, 0, (size_t)Nn * 4, stream);
    hipMemsetAsync(cursor, 0, (size_t)Nn * 4, stream);

    // fused setup: weight prep, x convert, degree count
    setup_kernel<<<2048, 256, 0, stream>>>(
        Wl1, Wr1, wt1h, wt1l, Wl2, Wr2, wt2h, wt2l,
        Wl3, Wr3, b3, Wout, bout, Wc, bc,
        x, xh, xl, dst, cnt, Nn, E);

    const int nb = (Nn + 1 + 4095) / 4096;   // 13
    scan_local_kernel<<<nb, 1024, 0, stream>>>(cnt, row_ptr, bsums, Nn);
    scan_bsums_kernel<<<1, 64, 0, stream>>>(bsums, nb);
    scan_add_kernel<<<nb, 1024, 0, stream>>>(row_ptr, bsums, Nn);
    scatter_kernel<<<2048, 256, 0, stream>>>(src, dst, row_ptr, cursor, esrc, E);

    const int gm64 = (Nn + 63) / 64;    // 782

    // Layer 1: [agg1 | x] -> 256, relu; emits hi/lo bf16 pair
    aggregate_pair_kernel<128><<<2048, 256, 0, stream>>>(xh, row_ptr, esrc, agg1h, agg1l, Nn);
    gemm_lds_kernel<128, 128, 256, true, false>
        <<<gm64, 256, 0, stream>>>(agg1h, agg1l, xh, xl,
                                   (const short8x*)wt1h, (const short8x*)wt1l,
                                   b1, hAh, hAl, nullptr, nullptr, nullptr, Nn);

    // Layer 2: [agg2 | h1] -> 256, relu; fused tu epilogue (no h2 materialized)
    aggregate_pair_kernel<256><<<2048, 256, 0, stream>>>(hAh, row_ptr, esrc, agg2h, agg2l, Nn);
    gemm_lds_kernel<256, 256, 256, true, true>
        <<<gm64, 256, 0, stream>>>(agg2h, agg2l, hAh, hAl,
                                   (const short8x*)wt2h, (const short8x*)wt2l,
                                   b2, nullptr, nullptr, Wc, bc, tu, Nn);

    // out = mean-gather(t) + u
    final_out_kernel<<<512, 256, 0, stream>>>(tu, row_ptr, esrc, (float*)d_out, Nn);
}

// Round 13
// 253.068 us; speedup vs baseline: 1.3844x; 1.0699x over previous
//
#include <hip/hip_runtime.h>

// ---------------------------------------------------------------------------
// GraphSAGE forward: 3x SAGEConv(mean) + ReLU(1,2) + final 128->2 projection.
// Activations carried as bf16 hi/lo pairs (split-bf16 3-term MFMA numerics).
// GEMM: BM=32 x BN=256, BK=64 double-buffered LDS A (round-10 proven sync:
// one __syncthreads per step, B reg-prefetched mid-step). Small tile -> 1563
// blocks, 18KB LDS -> high occupancy; barrier drain hidden by cross-block TLP.
// Layer3+out-proj collapsed to [256][4] Wc; tu fused into GEMM-2 epilogue.
// Setup (weight prep + x convert + degree count) fused into one kernel.
// ---------------------------------------------------------------------------

constexpr int D_IN  = 128;
constexpr int D_HID = 256;

typedef __attribute__((ext_vector_type(8))) short short8x;
typedef __attribute__((ext_vector_type(4))) float f32x4;

// ---------------- bf16 split helpers ----------------

__device__ inline unsigned bf16_rne(float f) {
    unsigned u = __float_as_uint(f);
    return (u + 0x7fffu + ((u >> 16) & 1u)) >> 16;
}

__device__ inline void split_pair(float v, unsigned& h, unsigned& l) {
    h = bf16_rne(v);
    float hf = __uint_as_float(h << 16);
    l = bf16_rne(v - hf);
}

// ---------------- fused setup: prep_wt x2, prep_wc, f32->pair(x), count_deg --

__device__ inline void prep_wt_elem(const float* __restrict__ Wl,
                                    const float* __restrict__ Wr,
                                    int K1, int K2, int Nc, int i,
                                    short* __restrict__ WTh, short* __restrict__ WTl) {
    const int KE = K1 + K2;
    const int KSTEPS = KE / 32;
    int e = i & 7;
    int t = i >> 3;
    int l = t & 63;
    int t2 = t >> 6;
    int k32 = t2 % KSTEPS;
    int n16 = t2 / KSTEPS;
    int n = n16 * 16 + (l & 15);
    int k = k32 * 32 + (l >> 4) * 8 + e;
    float w = (k < K1) ? Wl[(size_t)k * Nc + n] : Wr[(size_t)(k - K1) * Nc + n];
    unsigned h, lo;
    split_pair(w, h, lo);
    WTh[i] = (short)h;
    WTl[i] = (short)lo;
}

__global__ __launch_bounds__(256) void setup_kernel(
    const float* __restrict__ Wl1, const float* __restrict__ Wr1,
    short* __restrict__ wt1h, short* __restrict__ wt1l,
    const float* __restrict__ Wl2, const float* __restrict__ Wr2,
    short* __restrict__ wt2h, short* __restrict__ wt2l,
    const float* __restrict__ Wl3, const float* __restrict__ Wr3,
    const float* __restrict__ b3, const float* __restrict__ Wout,
    const float* __restrict__ bout, float* __restrict__ Wc, float* __restrict__ bc,
    const float* __restrict__ x, unsigned short* __restrict__ xh,
    unsigned short* __restrict__ xl,
    const int* __restrict__ dst, int* __restrict__ cnt,
    int Nn, int E) {
    const int gtid = blockIdx.x * blockDim.x + threadIdx.x;
    const int gs = gridDim.x * blockDim.x;

    const int n8 = Nn * D_IN / 8;
    for (int i = gtid; i < n8; i += gs) {
        const float4* p = (const float4*)(x + (size_t)i * 8);
        float4 v0 = p[0], v1 = p[1];
        float f[8] = {v0.x, v0.y, v0.z, v0.w, v1.x, v1.y, v1.z, v1.w};
        unsigned h[8], l[8];
        #pragma unroll
        for (int j = 0; j < 8; ++j) split_pair(f[j], h[j], l[j]);
        uint4 qh, ql;
        qh.x = h[0] | (h[1] << 16); qh.y = h[2] | (h[3] << 16);
        qh.z = h[4] | (h[5] << 16); qh.w = h[6] | (h[7] << 16);
        ql.x = l[0] | (l[1] << 16); ql.y = l[2] | (l[3] << 16);
        ql.z = l[4] | (l[5] << 16); ql.w = l[6] | (l[7] << 16);
        *(uint4*)(xh + (size_t)i * 8) = qh;
        *(uint4*)(xl + (size_t)i * 8) = ql;
    }

    for (int i = gtid; i < E; i += gs)
        atomicAdd(&cnt[dst[i]], 1);

    for (int i = gtid; i < 256 * 256; i += gs)
        prep_wt_elem(Wl1, Wr1, 128, 128, 256, i, wt1h, wt1l);
    for (int i = gtid; i < 256 * 512; i += gs)
        prep_wt_elem(Wl2, Wr2, 256, 256, 256, i, wt2h, wt2l);

    for (int i = gtid; i < 1024; i += gs) {
        int hh = i >> 2, c = i & 3;
        const float* Ws = (c < 2) ? Wl3 : Wr3;
        int o = c & 1;
        float s = 0.f;
        for (int e = 0; e < 128; ++e) s += Ws[hh * 128 + e] * Wout[e * 2 + o];
        Wc[hh * 4 + c] = s;
    }
    if (gtid < 2) {
        float sb = 0.f;
        for (int e = 0; e < 128; ++e) sb += b3[e] * Wout[e * 2 + gtid];
        bc[gtid] = sb + bout[gtid];
    }
}

// ---------------- CSR scan + scatter ----------------

__global__ __launch_bounds__(1024) void scan_local_kernel(
    const int* __restrict__ cnt, int* __restrict__ row_ptr,
    int* __restrict__ bsums, int Nn) {
    __shared__ int wsum[16];
    const int tid = threadIdx.x, lane = tid & 63, wid = tid >> 6;
    const int idx0 = blockIdx.x * 4096 + tid * 4;
    int v[4];
    #pragma unroll
    for (int j = 0; j < 4; ++j) {
        int idx = idx0 + j;
        v[j] = (idx < Nn) ? cnt[idx] : 0;
    }
    int s = v[0] + v[1] + v[2] + v[3];
    int xi = s;
    #pragma unroll
    for (int o = 1; o < 64; o <<= 1) {
        int t = __shfl_up(xi, o, 64);
        if (lane >= o) xi += t;
    }
    if (lane == 63) wsum[wid] = xi;
    __syncthreads();
    if (wid == 0) {
        int t = (lane < 16) ? wsum[lane] : 0;
        #pragma unroll
        for (int o = 1; o < 16; o <<= 1) {
            int u = __shfl_up(t, o, 64);
            if (lane >= o) t += u;
        }
        if (lane < 16) wsum[lane] = t;
    }
    __syncthreads();
    int off = (wid ? wsum[wid - 1] : 0) + xi - s;
    int run = off;
    #pragma unroll
    for (int j = 0; j < 4; ++j) {
        int idx = idx0 + j;
        if (idx <= Nn) row_ptr[idx] = run;
        run += v[j];
    }
    if (tid == 0) bsums[blockIdx.x] = wsum[15];
}

// each block redundantly scans bsums[0..b) (nb <= 13, cheap) then adds base.
__global__ __launch_bounds__(1024) void scan_add_kernel(
    int* __restrict__ row_ptr, const int* __restrict__ bsums, int Nn) {
    __shared__ int sbase;
    const int b = blockIdx.x;
    if (threadIdx.x == 0) {
        int s = 0;
        for (int i = 0; i < b; ++i) s += bsums[i];
        sbase = s;
    }
    __syncthreads();
    const int base = sbase;
    const int idx0 = b * 4096 + threadIdx.x * 4;
    #pragma unroll
    for (int j = 0; j < 4; ++j) {
        int idx = idx0 + j;
        if (idx <= Nn) row_ptr[idx] += base;
    }
}

__global__ void scatter_kernel(const int* __restrict__ src, const int* __restrict__ dst,
                               const int* __restrict__ row_ptr, int* __restrict__ cursor,
                               int* __restrict__ esrc, int E) {
    int stride = gridDim.x * blockDim.x;
    for (int i = blockIdx.x * blockDim.x + threadIdx.x; i < E; i += stride) {
        int d = dst[i];
        int p = atomicAdd(&cursor[d], 1);
        esrc[row_ptr[d] + p] = src[i];
    }
}

// ---------------- mean aggregation over bf16 rows -> hi/lo pair ------------

__device__ inline void addbf8(const uint4& q, float* a) {
    a[0] += __uint_as_float(q.x << 16); a[1] += __uint_as_float(q.x & 0xFFFF0000u);
    a[2] += __uint_as_float(q.y << 16); a[3] += __uint_as_float(q.y & 0xFFFF0000u);
    a[4] += __uint_as_float(q.z << 16); a[5] += __uint_as_float(q.z & 0xFFFF0000u);
    a[6] += __uint_as_float(q.w << 16); a[7] += __uint_as_float(q.w & 0xFFFF0000u);
}

template <int D>
__global__ __launch_bounds__(256) void aggregate_pair_kernel(
    const unsigned short* __restrict__ xb, const int* __restrict__ row_ptr,
    const int* __restrict__ esrc, unsigned short* __restrict__ aggh,
    unsigned short* __restrict__ aggl, int Nn) {
    constexpr int LPN = D / 8;
    constexpr int NPW = 64 / LPN;
    const int lane = threadIdx.x & 63;
    const int sub = lane / LPN;
    const int sl = lane % LPN;
    const int wave = (blockIdx.x * blockDim.x + threadIdx.x) >> 6;
    const int nw = (gridDim.x * blockDim.x) >> 6;
    for (int base = wave * NPW; base < Nn; base += nw * NPW) {
        int node = base + sub;
        if (node >= Nn) continue;
        int beg = row_ptr[node], end = row_ptr[node + 1];
        float a0[8] = {}, a1[8] = {}, a2[8] = {}, a3[8] = {};
        int e = beg;
        for (; e + 4 <= end; e += 4) {
            int s0 = esrc[e], s1 = esrc[e + 1], s2 = esrc[e + 2], s3 = esrc[e + 3];
            uint4 q0 = *(const uint4*)(xb + (size_t)s0 * D + sl * 8);
            uint4 q1 = *(const uint4*)(xb + (size_t)s1 * D + sl * 8);
            uint4 q2 = *(const uint4*)(xb + (size_t)s2 * D + sl * 8);
            uint4 q3 = *(const uint4*)(xb + (size_t)s3 * D + sl * 8);
            addbf8(q0, a0); addbf8(q1, a1); addbf8(q2, a2); addbf8(q3, a3);
        }
        for (; e < end; ++e) {
            int s0 = esrc[e];
            uint4 q0 = *(const uint4*)(xb + (size_t)s0 * D + sl * 8);
            addbf8(q0, a0);
        }
        float inv = 1.0f / fmaxf((float)(end - beg), 1.0f);
        unsigned h[8], l[8];
        #pragma unroll
        for (int i = 0; i < 8; ++i)
            split_pair((a0[i] + a1[i] + a2[i] + a3[i]) * inv, h[i], l[i]);
        uint4 qh, ql;
        qh.x = h[0] | (h[1] << 16); qh.y = h[2] | (h[3] << 16);
        qh.z = h[4] | (h[5] << 16); qh.w = h[6] | (h[7] << 16);
        ql.x = l[0] | (l[1] << 16); ql.y = l[2] | (l[3] << 16);
        ql.z = l[4] | (l[5] << 16); ql.w = l[6] | (l[7] << 16);
        *(uint4*)(aggh + (size_t)node * D + sl * 8) = qh;
        *(uint4*)(aggl + (size_t)node * D + sl * 8) = ql;
    }
}

// ---------------- LDS-staged split-bf16 MFMA GEMM, BM=32, BK=64 ----------
// C = act([A1|A2] @ Wcat + b). A pre-split bf16 pairs in global.
// Block: 32 rows x 256 cols, 4 waves (wave wc owns cols wc*64..+63, all 32
// rows via 2 m-frags). sA[2][32][128] shorts: row = 256B = 16 chunks of 16B;
// chunks 0-7 = Ah (k=chunk*8), 8-15 = Al; XOR-swizzled by row&7 within
// 8-groups via pre-swizzled global_load_lds SOURCE (LDS dest linear).
// Per step: 2 x {ds_read frags + 24 MFMA} halves; B for half1 and next-half0
// reg-prefetched mid-step. One __syncthreads per step (round-10 proven sync).

template <int K1, int K2, int N, bool RELU, bool TU>
__global__ __launch_bounds__(256, 4) void gemm_lds_kernel(
    const unsigned short* __restrict__ A1h, const unsigned short* __restrict__ A1l,
    const unsigned short* __restrict__ A2h, const unsigned short* __restrict__ A2l,
    const short8x* __restrict__ WTh, const short8x* __restrict__ WTl,
    const float* __restrict__ bias,
    unsigned short* __restrict__ Ch, unsigned short* __restrict__ Cl,
    const float* __restrict__ Wc, const float* __restrict__ bc,
    float* __restrict__ tuout, int M) {
    constexpr int KEFF = K1 + K2;
    constexpr int KS64 = KEFF / 64;
    constexpr int KS32 = KEFF / 32;
    __shared__ __attribute__((aligned(16))) unsigned short sA[2][32][128]; // 16 KB
    __shared__ float4 sRed[4][32];                                         // 2 KB
    const int tid = threadIdx.x, lane = tid & 63, wc = tid >> 6;
    const int bm = blockIdx.x * 32;

    // stage one BK=64 A-tile (Ah+Al, 8 KB) into sA[buf]; 2 gload_lds/thread.
    auto stage = [&](int buf, int ks) {
        int k0 = ks * 64;
        const unsigned short *Hb, *Lb; int kloc, Kx;
        if (k0 < K1) { Hb = A1h; Lb = A1l; kloc = k0;      Kx = K1; }
        else         { Hb = A2h; Lb = A2l; kloc = k0 - K1; Kx = K2; }
        #pragma unroll
        for (int q = 0; q < 2; ++q) {
            int r0 = wc * 8 + q * 4;                  // wave-uniform base row
            int rloc = r0 + (lane >> 4);
            int grow = bm + rloc; if (grow >= M) grow = M - 1;
            int p = lane & 15;                        // dest chunk position
            int c = ((p & 7) ^ (rloc & 7)) | (p & 8); // logical chunk at p
            const unsigned short* base = (c & 8) ? Lb : Hb;
            const unsigned short* g = base + (size_t)grow * Kx + kloc + (c & 7) * 8;
            __builtin_amdgcn_global_load_lds((const unsigned*)g,
                                             (unsigned*)&sA[buf][r0][0], 16, 0, 0);
        }
    };

    auto loadB = [&](int ks32, short8x* bh, short8x* bl) {
        #pragma unroll
        for (int n = 0; n < 4; ++n) {
            size_t widx = ((size_t)(wc * 4 + n) * KS32 + ks32) * 64 + lane;
            bh[n] = WTh[widx];
            bl[n] = WTl[widx];
        }
    };

    f32x4 acc[2][4];
    #pragma unroll
    for (int m = 0; m < 2; ++m)
        #pragma unroll
        for (int n = 0; n < 4; ++n)
            acc[m][n] = (f32x4){0.f, 0.f, 0.f, 0.f};

    short8x bhC[4], blC[4], bhD[4], blD[4], bhN[4], blN[4];
    stage(0, 0);
    loadB(0, bhC, blC);
    __syncthreads();

    #pragma unroll
    for (int ks = 0; ks < KS64; ++ks) {
        const int cur = ks & 1;
        if (ks + 1 < KS64) stage(cur ^ 1, ks + 1);   // prefetch next A-tile
        loadB(ks * 2 + 1, bhD, blD);                 // this step's half1 B

        // ---- half 0 (k = ks*64 .. +32), B = bhC (ready) ----
        {
            short8x ah[2], al[2];
            #pragma unroll
            for (int m = 0; m < 2; ++m) {
                const unsigned short* rp = &sA[cur][m * 16 + (lane & 15)][0];
                int cpos = ((lane >> 4) ^ (lane & 7));          // kh=0
                ah[m] = *(const short8x*)(rp + cpos * 8);
                al[m] = *(const short8x*)(rp + cpos * 8 + 64);
            }
            #pragma unroll
            for (int m = 0; m < 2; ++m)
                #pragma unroll
                for (int n = 0; n < 4; ++n) {
                    acc[m][n] = __builtin_amdgcn_mfma_f32_16x16x32_bf16(ah[m], bhC[n], acc[m][n], 0, 0, 0);
                    acc[m][n] = __builtin_amdgcn_mfma_f32_16x16x32_bf16(ah[m], blC[n], acc[m][n], 0, 0, 0);
                    acc[m][n] = __builtin_amdgcn_mfma_f32_16x16x32_bf16(al[m], bhC[n], acc[m][n], 0, 0, 0);
                }
        }

        if (ks + 1 < KS64) loadB((ks + 1) * 2, bhN, blN);  // next step half0 B

        // ---- half 1 (k = ks*64+32 .. +64), B = bhD ----
        {
            short8x ah[2], al[2];
            #pragma unroll
            for (int m = 0; m < 2; ++m) {
                const unsigned short* rp = &sA[cur][m * 16 + (lane & 15)][0];
                int cpos = ((4 + (lane >> 4)) ^ (lane & 7));    // kh=1
                ah[m] = *(const short8x*)(rp + cpos * 8);
                al[m] = *(const short8x*)(rp + cpos * 8 + 64);
            }
            #pragma unroll
            for (int m = 0; m < 2; ++m)
                #pragma unroll
                for (int n = 0; n < 4; ++n) {
                    acc[m][n] = __builtin_amdgcn_mfma_f32_16x16x32_bf16(ah[m], bhD[n], acc[m][n], 0, 0, 0);
                    acc[m][n] = __builtin_amdgcn_mfma_f32_16x16x32_bf16(ah[m], blD[n], acc[m][n], 0, 0, 0);
                    acc[m][n] = __builtin_amdgcn_mfma_f32_16x16x32_bf16(al[m], bhD[n], acc[m][n], 0, 0, 0);
                }
        }

        __syncthreads();   // drains A-stage + B prefetch before buffer swap
        if (ks + 1 < KS64) {
            #pragma unroll
            for (int n = 0; n < 4; ++n) {   // renamed away by full unroll
                bhC[n] = bhN[n];
                blC[n] = blN[n];
            }
        }
    }

    float bv[4];
    #pragma unroll
    for (int n = 0; n < 4; ++n) bv[n] = bias[wc * 64 + n * 16 + (lane & 15)];

    if constexpr (!TU) {
        #pragma unroll
        for (int n = 0; n < 4; ++n) {
            const int col = wc * 64 + n * 16 + (lane & 15);
            #pragma unroll
            for (int m = 0; m < 2; ++m) {
                #pragma unroll
                for (int j = 0; j < 4; ++j) {
                    int row = bm + m * 16 + (lane >> 4) * 4 + j;
                    if (row < M) {
                        float v = acc[m][n][j] + bv[n];
                        if (RELU) v = fmaxf(v, 0.f);
                        unsigned h, l;
                        split_pair(v, h, l);
                        Ch[(size_t)row * N + col] = (unsigned short)h;
                        Cl[(size_t)row * N + col] = (unsigned short)l;
                    }
                }
            }
        }
    } else {
        float4 wcv[4];
        #pragma unroll
        for (int n = 0; n < 4; ++n)
            wcv[n] = *(const float4*)(Wc + (size_t)(wc * 64 + n * 16 + (lane & 15)) * 4);
        #pragma unroll
        for (int m = 0; m < 2; ++m) {
            #pragma unroll
            for (int j = 0; j < 4; ++j) {
                float4 p = make_float4(0.f, 0.f, 0.f, 0.f);
                #pragma unroll
                for (int n = 0; n < 4; ++n) {
                    float v = acc[m][n][j] + bv[n];
                    if (RELU) v = fmaxf(v, 0.f);
                    p.x += v * wcv[n].x; p.y += v * wcv[n].y;
                    p.z += v * wcv[n].z; p.w += v * wcv[n].w;
                }
                #pragma unroll
                for (int mk = 8; mk >= 1; mk >>= 1) {
                    p.x += __shfl_xor(p.x, mk, 64);
                    p.y += __shfl_xor(p.y, mk, 64);
                    p.z += __shfl_xor(p.z, mk, 64);
                    p.w += __shfl_xor(p.w, mk, 64);
                }
                if ((lane & 15) == 0)
                    sRed[wc][m * 16 + (lane >> 4) * 4 + j] = p;
            }
        }
        __syncthreads();
        if (tid < 32) {
            int row = bm + tid;
            float4 a = sRed[0][tid], b2 = sRed[1][tid], c2 = sRed[2][tid], d2 = sRed[3][tid];
            float4 t;
            t.x = a.x + b2.x + c2.x + d2.x;
            t.y = a.y + b2.y + c2.y + d2.y;
            t.z = a.z + b2.z + c2.z + d2.z + bc[0];
            t.w = a.w + b2.w + c2.w + d2.w + bc[1];
            if (row < M) *(float4*)(tuout + (size_t)row * 4) = t;
        }
    }
}

// ---------------- out_i = mean_j t_j + u_i  (D=2 gather, L2-resident) ------

__global__ __launch_bounds__(256) void final_out_kernel(
    const float* __restrict__ tu, const int* __restrict__ row_ptr,
    const int* __restrict__ esrc, float* __restrict__ out, int Nn) {
    int stride = gridDim.x * blockDim.x;
    for (int i = blockIdx.x * blockDim.x + threadIdx.x; i < Nn; i += stride) {
        int beg = row_ptr[i], end = row_ptr[i + 1];
        float s0 = 0.f, s1 = 0.f;
        for (int e = beg; e < end; ++e) {
            int s = esrc[e];
            float2 tv = *(const float2*)(tu + (size_t)s * 4);
            s0 += tv.x; s1 += tv.y;
        }
        float inv = 1.0f / fmaxf((float)(end - beg), 1.0f);
        float u0 = tu[(size_t)i * 4 + 2], u1 = tu[(size_t)i * 4 + 3];
        *(float2*)(out + (size_t)i * 2) = make_float2(s0 * inv + u0, s1 * inv + u1);
    }
}

// ---------------- launch ----------------

extern "C" void kernel_launch(void* const* d_in, const int* in_sizes, int n_in,
                              void* d_out, int out_size, void* d_ws, size_t ws_size,
                              hipStream_t stream) {
    const float* x    = (const float*)d_in[0];
    const int*   ei   = (const int*)d_in[1];
    const float* Wl1  = (const float*)d_in[2];
    const float* Wr1  = (const float*)d_in[3];
    const float* b1   = (const float*)d_in[4];
    const float* Wl2  = (const float*)d_in[5];
    const float* Wr2  = (const float*)d_in[6];
    const float* b2   = (const float*)d_in[7];
    const float* Wl3  = (const float*)d_in[8];
    const float* Wr3  = (const float*)d_in[9];
    const float* b3   = (const float*)d_in[10];
    const float* Wout = (const float*)d_in[11];
    const float* bout = (const float*)d_in[12];

    const int Nn = in_sizes[0] / D_IN;     // 50000
    const int E  = in_sizes[1] / 2;        // 600000

    char* ws = (char*)d_ws;
    size_t off = 0;
    auto alloc = [&](size_t b) { size_t o = off; off = (off + b + 255) & ~(size_t)255; return o; };

    unsigned short* xh    = (unsigned short*)(ws + alloc((size_t)Nn * D_IN * 2));
    unsigned short* xl    = (unsigned short*)(ws + alloc((size_t)Nn * D_IN * 2));
    unsigned short* agg1h = (unsigned short*)(ws + alloc((size_t)Nn * D_IN * 2));
    unsigned short* agg1l = (unsigned short*)(ws + alloc((size_t)Nn * D_IN * 2));
    int*   row_ptr = (int*)(ws + alloc((size_t)(Nn + 1) * 4));
    int*   cnt     = (int*)(ws + alloc((size_t)Nn * 4));
    int*   cursor  = (int*)(ws + alloc((size_t)Nn * 4));
    int*   bsums   = (int*)(ws + alloc((size_t)256 * 4));
    int*   esrc    = (int*)(ws + alloc((size_t)E * 4));
    unsigned short* hAh   = (unsigned short*)(ws + alloc((size_t)Nn * D_HID * 2));
    unsigned short* hAl   = (unsigned short*)(ws + alloc((size_t)Nn * D_HID * 2));
    unsigned short* agg2h = (unsigned short*)(ws + alloc((size_t)Nn * D_HID * 2));
    unsigned short* agg2l = (unsigned short*)(ws + alloc((size_t)Nn * D_HID * 2));
    float* tu      = (float*)(ws + alloc((size_t)Nn * 4 * 4));
    float* Wc      = (float*)(ws + alloc((size_t)256 * 4 * 4));
    float* bc      = (float*)(ws + alloc((size_t)2 * 4));
    short* wt1h    = (short*)(ws + alloc((size_t)256 * 256 * 2));
    short* wt1l    = (short*)(ws + alloc((size_t)256 * 256 * 2));
    short* wt2h    = (short*)(ws + alloc((size_t)256 * 512 * 2));
    short* wt2l    = (short*)(ws + alloc((size_t)256 * 512 * 2));

    const int* src = ei;
    const int* dst = ei + E;

    hipMemsetAsync(cnt, 0, (size_t)Nn * 4, stream);
    hipMemsetAsync(cursor, 0, (size_t)Nn * 4, stream);

    // fused setup: weight prep, x convert, degree count
    setup_kernel<<<2048, 256, 0, stream>>>(
        Wl1, Wr1, wt1h, wt1l, Wl2, Wr2, wt2h, wt2l,
        Wl3, Wr3, b3, Wout, bout, Wc, bc,
        x, xh, xl, dst, cnt, Nn, E);

    const int nb = (Nn + 1 + 4095) / 4096;   // 13
    scan_local_kernel<<<nb, 1024, 0, stream>>>(cnt, row_ptr, bsums, Nn);
    scan_add_kernel<<<nb, 1024, 0, stream>>>(row_ptr, bsums, Nn);
    scatter_kernel<<<2048, 256, 0, stream>>>(src, dst, row_ptr, cursor, esrc, E);

    const int gm32 = (Nn + 31) / 32;    // 1563

    // Layer 1: [agg1 | x] -> 256, relu; emits hi/lo bf16 pair
    aggregate_pair_kernel<128><<<2048, 256, 0, stream>>>(xh, row_ptr, esrc, agg1h, agg1l, Nn);
    gemm_lds_kernel<128, 128, 256, true, false>
        <<<gm32, 256, 0, stream>>>(agg1h, agg1l, xh, xl,
                                   (const short8x*)wt1h, (const short8x*)wt1l,
                                   b1, hAh, hAl, nullptr, nullptr, nullptr, Nn);

    // Layer 2: [agg2 | h1] -> 256, relu; fused tu epilogue (no h2 materialized)
    aggregate_pair_kernel<256><<<2048, 256, 0, stream>>>(hAh, row_ptr, esrc, agg2h, agg2l, Nn);
    gemm_lds_kernel<256, 256, 256, true, true>
        <<<gm32, 256, 0, stream>>>(agg2h, agg2l, hAh, hAl,
                                   (const short8x*)wt2h, (const short8x*)wt2l,
                                   b2, nullptr, nullptr, Wc, bc, tu, Nn);

    // out = mean-gather(t) + u
    final_out_kernel<<<512, 256, 0, stream>>>(tu, row_ptr, esrc, (float*)d_out, Nn);
}

// Round 14
// 212.483 us; speedup vs baseline: 1.6488x; 1.1910x over previous
//
#include <hip/hip_runtime.h>

// ---------------------------------------------------------------------------
// GraphSAGE forward: 3x SAGEConv(mean) + ReLU(1,2) + final 128->2 projection.
// Pure bf16 (1-term) MFMA numerics: activations and weights RNE-rounded to
// bf16 (error budget ~0.03 vs 0.0609 threshold). GEMM: BM=32 x BN=256, BK=64
// double-buffered LDS A (round-13 proven sync: one __syncthreads per step,
// B reg-prefetched mid-step), XOR-swizzled gload_lds source.
// Layer3+out-proj collapsed to [256][4] Wc; tu fused into GEMM-2 epilogue.
// Setup (weight prep + x convert + degree count) fused into one kernel.
// ---------------------------------------------------------------------------

constexpr int D_IN  = 128;
constexpr int D_HID = 256;

typedef __attribute__((ext_vector_type(8))) short short8x;
typedef __attribute__((ext_vector_type(4))) float f32x4;

__device__ inline unsigned bf16_rne(float f) {
    unsigned u = __float_as_uint(f);
    return (u + 0x7fffu + ((u >> 16) & 1u)) >> 16;
}

// ---------------- fused setup: prep_wt x2, prep_wc, f32->bf16(x), count_deg --

__device__ inline void prep_wt_elem(const float* __restrict__ Wl,
                                    const float* __restrict__ Wr,
                                    int K1, int K2, int Nc, int i,
                                    short* __restrict__ WTh) {
    const int KE = K1 + K2;
    const int KSTEPS = KE / 32;
    int e = i & 7;
    int t = i >> 3;
    int l = t & 63;
    int t2 = t >> 6;
    int k32 = t2 % KSTEPS;
    int n16 = t2 / KSTEPS;
    int n = n16 * 16 + (l & 15);
    int k = k32 * 32 + (l >> 4) * 8 + e;
    float w = (k < K1) ? Wl[(size_t)k * Nc + n] : Wr[(size_t)(k - K1) * Nc + n];
    WTh[i] = (short)bf16_rne(w);
}

__global__ __launch_bounds__(256) void setup_kernel(
    const float* __restrict__ Wl1, const float* __restrict__ Wr1,
    short* __restrict__ wt1h,
    const float* __restrict__ Wl2, const float* __restrict__ Wr2,
    short* __restrict__ wt2h,
    const float* __restrict__ Wl3, const float* __restrict__ Wr3,
    const float* __restrict__ b3, const float* __restrict__ Wout,
    const float* __restrict__ bout, float* __restrict__ Wc, float* __restrict__ bc,
    const float* __restrict__ x, unsigned short* __restrict__ xb,
    const int* __restrict__ dst, int* __restrict__ cnt,
    int Nn, int E) {
    const int gtid = blockIdx.x * blockDim.x + threadIdx.x;
    const int gs = gridDim.x * blockDim.x;

    const int n8 = Nn * D_IN / 8;
    for (int i = gtid; i < n8; i += gs) {
        const float4* p = (const float4*)(x + (size_t)i * 8);
        float4 v0 = p[0], v1 = p[1];
        float f[8] = {v0.x, v0.y, v0.z, v0.w, v1.x, v1.y, v1.z, v1.w};
        unsigned h[8];
        #pragma unroll
        for (int j = 0; j < 8; ++j) h[j] = bf16_rne(f[j]);
        uint4 qh;
        qh.x = h[0] | (h[1] << 16); qh.y = h[2] | (h[3] << 16);
        qh.z = h[4] | (h[5] << 16); qh.w = h[6] | (h[7] << 16);
        *(uint4*)(xb + (size_t)i * 8) = qh;
    }

    for (int i = gtid; i < E; i += gs)
        atomicAdd(&cnt[dst[i]], 1);

    for (int i = gtid; i < 256 * 256; i += gs)
        prep_wt_elem(Wl1, Wr1, 128, 128, 256, i, wt1h);
    for (int i = gtid; i < 256 * 512; i += gs)
        prep_wt_elem(Wl2, Wr2, 256, 256, 256, i, wt2h);

    for (int i = gtid; i < 1024; i += gs) {
        int hh = i >> 2, c = i & 3;
        const float* Ws = (c < 2) ? Wl3 : Wr3;
        int o = c & 1;
        float s = 0.f;
        for (int e = 0; e < 128; ++e) s += Ws[hh * 128 + e] * Wout[e * 2 + o];
        Wc[hh * 4 + c] = s;
    }
    if (gtid < 2) {
        float sb = 0.f;
        for (int e = 0; e < 128; ++e) sb += b3[e] * Wout[e * 2 + gtid];
        bc[gtid] = sb + bout[gtid];
    }
}

// ---------------- CSR scan + scatter ----------------

__global__ __launch_bounds__(1024) void scan_local_kernel(
    const int* __restrict__ cnt, int* __restrict__ row_ptr,
    int* __restrict__ bsums, int Nn) {
    __shared__ int wsum[16];
    const int tid = threadIdx.x, lane = tid & 63, wid = tid >> 6;
    const int idx0 = blockIdx.x * 4096 + tid * 4;
    int v[4];
    #pragma unroll
    for (int j = 0; j < 4; ++j) {
        int idx = idx0 + j;
        v[j] = (idx < Nn) ? cnt[idx] : 0;
    }
    int s = v[0] + v[1] + v[2] + v[3];
    int xi = s;
    #pragma unroll
    for (int o = 1; o < 64; o <<= 1) {
        int t = __shfl_up(xi, o, 64);
        if (lane >= o) xi += t;
    }
    if (lane == 63) wsum[wid] = xi;
    __syncthreads();
    if (wid == 0) {
        int t = (lane < 16) ? wsum[lane] : 0;
        #pragma unroll
        for (int o = 1; o < 16; o <<= 1) {
            int u = __shfl_up(t, o, 64);
            if (lane >= o) t += u;
        }
        if (lane < 16) wsum[lane] = t;
    }
    __syncthreads();
    int off = (wid ? wsum[wid - 1] : 0) + xi - s;
    int run = off;
    #pragma unroll
    for (int j = 0; j < 4; ++j) {
        int idx = idx0 + j;
        if (idx <= Nn) row_ptr[idx] = run;
        run += v[j];
    }
    if (tid == 0) bsums[blockIdx.x] = wsum[15];
}

__global__ __launch_bounds__(1024) void scan_add_kernel(
    int* __restrict__ row_ptr, const int* __restrict__ bsums, int Nn) {
    __shared__ int sbase;
    const int b = blockIdx.x;
    if (threadIdx.x == 0) {
        int s = 0;
        for (int i = 0; i < b; ++i) s += bsums[i];
        sbase = s;
    }
    __syncthreads();
    const int base = sbase;
    const int idx0 = b * 4096 + threadIdx.x * 4;
    #pragma unroll
    for (int j = 0; j < 4; ++j) {
        int idx = idx0 + j;
        if (idx <= Nn) row_ptr[idx] += base;
    }
}

__global__ void scatter_kernel(const int* __restrict__ src, const int* __restrict__ dst,
                               const int* __restrict__ row_ptr, int* __restrict__ cursor,
                               int* __restrict__ esrc, int E) {
    int stride = gridDim.x * blockDim.x;
    for (int i = blockIdx.x * blockDim.x + threadIdx.x; i < E; i += stride) {
        int d = dst[i];
        int p = atomicAdd(&cursor[d], 1);
        esrc[row_ptr[d] + p] = src[i];
    }
}

// ---------------- mean aggregation over bf16 rows -> bf16 ------------

__device__ inline void addbf8(const uint4& q, float* a) {
    a[0] += __uint_as_float(q.x << 16); a[1] += __uint_as_float(q.x & 0xFFFF0000u);
    a[2] += __uint_as_float(q.y << 16); a[3] += __uint_as_float(q.y & 0xFFFF0000u);
    a[4] += __uint_as_float(q.z << 16); a[5] += __uint_as_float(q.z & 0xFFFF0000u);
    a[6] += __uint_as_float(q.w << 16); a[7] += __uint_as_float(q.w & 0xFFFF0000u);
}

template <int D>
__global__ __launch_bounds__(256) void aggregate_bf16_kernel(
    const unsigned short* __restrict__ xb, const int* __restrict__ row_ptr,
    const int* __restrict__ esrc, unsigned short* __restrict__ aggb, int Nn) {
    constexpr int LPN = D / 8;
    constexpr int NPW = 64 / LPN;
    const int lane = threadIdx.x & 63;
    const int sub = lane / LPN;
    const int sl = lane % LPN;
    const int wave = (blockIdx.x * blockDim.x + threadIdx.x) >> 6;
    const int nw = (gridDim.x * blockDim.x) >> 6;
    for (int base = wave * NPW; base < Nn; base += nw * NPW) {
        int node = base + sub;
        if (node >= Nn) continue;
        int beg = row_ptr[node], end = row_ptr[node + 1];
        float a0[8] = {}, a1[8] = {}, a2[8] = {}, a3[8] = {};
        int e = beg;
        for (; e + 4 <= end; e += 4) {
            int s0 = esrc[e], s1 = esrc[e + 1], s2 = esrc[e + 2], s3 = esrc[e + 3];
            uint4 q0 = *(const uint4*)(xb + (size_t)s0 * D + sl * 8);
            uint4 q1 = *(const uint4*)(xb + (size_t)s1 * D + sl * 8);
            uint4 q2 = *(const uint4*)(xb + (size_t)s2 * D + sl * 8);
            uint4 q3 = *(const uint4*)(xb + (size_t)s3 * D + sl * 8);
            addbf8(q0, a0); addbf8(q1, a1); addbf8(q2, a2); addbf8(q3, a3);
        }
        for (; e < end; ++e) {
            int s0 = esrc[e];
            uint4 q0 = *(const uint4*)(xb + (size_t)s0 * D + sl * 8);
            addbf8(q0, a0);
        }
        float inv = 1.0f / fmaxf((float)(end - beg), 1.0f);
        unsigned h[8];
        #pragma unroll
        for (int i = 0; i < 8; ++i)
            h[i] = bf16_rne((a0[i] + a1[i] + a2[i] + a3[i]) * inv);
        uint4 qh;
        qh.x = h[0] | (h[1] << 16); qh.y = h[2] | (h[3] << 16);
        qh.z = h[4] | (h[5] << 16); qh.w = h[6] | (h[7] << 16);
        *(uint4*)(aggb + (size_t)node * D + sl * 8) = qh;
    }
}

// ---------------- LDS-staged bf16 MFMA GEMM, BM=32, BK=64 ----------
// C = act([A1|A2] @ Wcat + b), all bf16 operands, fp32 accumulate.
// Block: 32 rows x 256 cols, 4 waves (wave wc owns cols wc*64..+63).
// sA[2][32][64] shorts: row = 128B = 8 chunks of 16B, XOR-swizzled by row&7
// via pre-swizzled global_load_lds SOURCE (LDS dest linear; 1 load/thread).
// Per step: 2 halves x {2 ds_read + 8 MFMA}; B for half1 and next-half0
// reg-prefetched mid-step. One __syncthreads per step (round-13 proven sync).

template <int K1, int K2, int N, bool RELU, bool TU>
__global__ __launch_bounds__(256, 4) void gemm_lds_kernel(
    const unsigned short* __restrict__ A1, const unsigned short* __restrict__ A2,
    const short8x* __restrict__ WTh, const float* __restrict__ bias,
    unsigned short* __restrict__ C,
    const float* __restrict__ Wc, const float* __restrict__ bc,
    float* __restrict__ tuout, int M) {
    constexpr int KEFF = K1 + K2;
    constexpr int KS64 = KEFF / 64;
    constexpr int KS32 = KEFF / 32;
    __shared__ __attribute__((aligned(16))) unsigned short sA[2][32][64]; // 8 KB
    __shared__ float4 sRed[4][32];                                        // 2 KB
    const int tid = threadIdx.x, lane = tid & 63, wc = tid >> 6;
    const int bm = blockIdx.x * 32;

    // stage one BK=64 A-tile (4 KB) into sA[buf]; 1 gload_lds per thread.
    auto stage = [&](int buf, int ks) {
        int k0 = ks * 64;
        const unsigned short* Ab; int kloc, Kx;
        if (k0 < K1) { Ab = A1; kloc = k0;      Kx = K1; }
        else         { Ab = A2; kloc = k0 - K1; Kx = K2; }
        int r0 = wc * 8;                           // wave-uniform base row
        int rloc = r0 + (lane >> 3);
        int grow = bm + rloc; if (grow >= M) grow = M - 1;
        int c = (lane & 7) ^ (lane >> 3);          // rloc&7 == lane>>3
        const unsigned short* g = Ab + (size_t)grow * Kx + kloc + c * 8;
        __builtin_amdgcn_global_load_lds((const unsigned*)g,
                                         (unsigned*)&sA[buf][r0][0], 16, 0, 0);
    };

    auto loadB = [&](int ks32, short8x* bh) {
        #pragma unroll
        for (int n = 0; n < 4; ++n)
            bh[n] = WTh[((size_t)(wc * 4 + n) * KS32 + ks32) * 64 + lane];
    };

    f32x4 acc[2][4];
    #pragma unroll
    for (int m = 0; m < 2; ++m)
        #pragma unroll
        for (int n = 0; n < 4; ++n)
            acc[m][n] = (f32x4){0.f, 0.f, 0.f, 0.f};

    short8x bhC[4], bhD[4], bhN[4];
    stage(0, 0);
    loadB(0, bhC);
    __syncthreads();

    #pragma unroll
    for (int ks = 0; ks < KS64; ++ks) {
        const int cur = ks & 1;
        if (ks + 1 < KS64) stage(cur ^ 1, ks + 1);   // prefetch next A-tile
        loadB(ks * 2 + 1, bhD);                      // this step's half1 B

        // ---- half 0 ----
        {
            short8x a0[2];
            #pragma unroll
            for (int m = 0; m < 2; ++m) {
                const unsigned short* rp = &sA[cur][m * 16 + (lane & 15)][0];
                int pos = (lane >> 4) ^ (lane & 7);
                a0[m] = *(const short8x*)(rp + pos * 8);
            }
            #pragma unroll
            for (int m = 0; m < 2; ++m)
                #pragma unroll
                for (int n = 0; n < 4; ++n)
                    acc[m][n] = __builtin_amdgcn_mfma_f32_16x16x32_bf16(a0[m], bhC[n], acc[m][n], 0, 0, 0);
        }

        if (ks + 1 < KS64) loadB((ks + 1) * 2, bhN); // next step half0 B

        // ---- half 1 ----
        {
            short8x a1[2];
            #pragma unroll
            for (int m = 0; m < 2; ++m) {
                const unsigned short* rp = &sA[cur][m * 16 + (lane & 15)][0];
                int pos = (4 + (lane >> 4)) ^ (lane & 7);
                a1[m] = *(const short8x*)(rp + pos * 8);
            }
            #pragma unroll
            for (int m = 0; m < 2; ++m)
                #pragma unroll
                for (int n = 0; n < 4; ++n)
                    acc[m][n] = __builtin_amdgcn_mfma_f32_16x16x32_bf16(a1[m], bhD[n], acc[m][n], 0, 0, 0);
        }

        __syncthreads();   // drains A-stage + B prefetch before buffer swap
        if (ks + 1 < KS64) {
            #pragma unroll
            for (int n = 0; n < 4; ++n) bhC[n] = bhN[n];  // renamed by unroll
        }
    }

    float bv[4];
    #pragma unroll
    for (int n = 0; n < 4; ++n) bv[n] = bias[wc * 64 + n * 16 + (lane & 15)];

    if constexpr (!TU) {
        #pragma unroll
        for (int n = 0; n < 4; ++n) {
            const int col = wc * 64 + n * 16 + (lane & 15);
            #pragma unroll
            for (int m = 0; m < 2; ++m) {
                #pragma unroll
                for (int j = 0; j < 4; ++j) {
                    int row = bm + m * 16 + (lane >> 4) * 4 + j;
                    if (row < M) {
                        float v = acc[m][n][j] + bv[n];
                        if (RELU) v = fmaxf(v, 0.f);
                        C[(size_t)row * N + col] = (unsigned short)bf16_rne(v);
                    }
                }
            }
        }
    } else {
        float4 wcv[4];
        #pragma unroll
        for (int n = 0; n < 4; ++n)
            wcv[n] = *(const float4*)(Wc + (size_t)(wc * 64 + n * 16 + (lane & 15)) * 4);
        #pragma unroll
        for (int m = 0; m < 2; ++m) {
            #pragma unroll
            for (int j = 0; j < 4; ++j) {
                float4 p = make_float4(0.f, 0.f, 0.f, 0.f);
                #pragma unroll
                for (int n = 0; n < 4; ++n) {
                    float v = acc[m][n][j] + bv[n];
                    if (RELU) v = fmaxf(v, 0.f);
                    p.x += v * wcv[n].x; p.y += v * wcv[n].y;
                    p.z += v * wcv[n].z; p.w += v * wcv[n].w;
                }
                #pragma unroll
                for (int mk = 8; mk >= 1; mk >>= 1) {
                    p.x += __shfl_xor(p.x, mk, 64);
                    p.y += __shfl_xor(p.y, mk, 64);
                    p.z += __shfl_xor(p.z, mk, 64);
                    p.w += __shfl_xor(p.w, mk, 64);
                }
                if ((lane & 15) == 0)
                    sRed[wc][m * 16 + (lane >> 4) * 4 + j] = p;
            }
        }
        __syncthreads();
        if (tid < 32) {
            int row = bm + tid;
            float4 a = sRed[0][tid], b2 = sRed[1][tid], c2 = sRed[2][tid], d2 = sRed[3][tid];
            float4 t;
            t.x = a.x + b2.x + c2.x + d2.x;
            t.y = a.y + b2.y + c2.y + d2.y;
            t.z = a.z + b2.z + c2.z + d2.z + bc[0];
            t.w = a.w + b2.w + c2.w + d2.w + bc[1];
            if (row < M) *(float4*)(tuout + (size_t)row * 4) = t;
        }
    }
}

// ---------------- out_i = mean_j t_j + u_i  (D=2 gather, L2-resident) ------

__global__ __launch_bounds__(256) void final_out_kernel(
    const float* __restrict__ tu, const int* __restrict__ row_ptr,
    const int* __restrict__ esrc, float* __restrict__ out, int Nn) {
    int stride = gridDim.x * blockDim.x;
    for (int i = blockIdx.x * blockDim.x + threadIdx.x; i < Nn; i += stride) {
        int beg = row_ptr[i], end = row_ptr[i + 1];
        float s0 = 0.f, s1 = 0.f;
        for (int e = beg; e < end; ++e) {
            int s = esrc[e];
            float2 tv = *(const float2*)(tu + (size_t)s * 4);
            s0 += tv.x; s1 += tv.y;
        }
        float inv = 1.0f / fmaxf((float)(end - beg), 1.0f);
        float u0 = tu[(size_t)i * 4 + 2], u1 = tu[(size_t)i * 4 + 3];
        *(float2*)(out + (size_t)i * 2) = make_float2(s0 * inv + u0, s1 * inv + u1);
    }
}

// ---------------- launch ----------------

extern "C" void kernel_launch(void* const* d_in, const int* in_sizes, int n_in,
                              void* d_out, int out_size, void* d_ws, size_t ws_size,
                              hipStream_t stream) {
    const float* x    = (const float*)d_in[0];
    const int*   ei   = (const int*)d_in[1];
    const float* Wl1  = (const float*)d_in[2];
    const float* Wr1  = (const float*)d_in[3];
    const float* b1   = (const float*)d_in[4];
    const float* Wl2  = (const float*)d_in[5];
    const float* Wr2  = (const float*)d_in[6];
    const float* b2   = (const float*)d_in[7];
    const float* Wl3  = (const float*)d_in[8];
    const float* Wr3  = (const float*)d_in[9];
    const float* b3   = (const float*)d_in[10];
    const float* Wout = (const float*)d_in[11];
    const float* bout = (const float*)d_in[12];

    const int Nn = in_sizes[0] / D_IN;     // 50000
    const int E  = in_sizes[1] / 2;        // 600000

    char* ws = (char*)d_ws;
    size_t off = 0;
    auto alloc = [&](size_t b) { size_t o = off; off = (off + b + 255) & ~(size_t)255; return o; };

    unsigned short* xb    = (unsigned short*)(ws + alloc((size_t)Nn * D_IN * 2));
    unsigned short* agg1b = (unsigned short*)(ws + alloc((size_t)Nn * D_IN * 2));
    int*   row_ptr = (int*)(ws + alloc((size_t)(Nn + 1) * 4));
    int*   cnt     = (int*)(ws + alloc((size_t)Nn * 4));
    int*   cursor  = (int*)(ws + alloc((size_t)Nn * 4));
    int*   bsums   = (int*)(ws + alloc((size_t)256 * 4));
    int*   esrc    = (int*)(ws + alloc((size_t)E * 4));
    unsigned short* h1b   = (unsigned short*)(ws + alloc((size_t)Nn * D_HID * 2));
    unsigned short* agg2b = (unsigned short*)(ws + alloc((size_t)Nn * D_HID * 2));
    float* tu      = (float*)(ws + alloc((size_t)Nn * 4 * 4));
    float* Wc      = (float*)(ws + alloc((size_t)256 * 4 * 4));
    float* bc      = (float*)(ws + alloc((size_t)2 * 4));
    short* wt1h    = (short*)(ws + alloc((size_t)256 * 256 * 2));
    short* wt2h    = (short*)(ws + alloc((size_t)256 * 512 * 2));

    const int* src = ei;
    const int* dst = ei + E;

    hipMemsetAsync(cnt, 0, (size_t)Nn * 4, stream);
    hipMemsetAsync(cursor, 0, (size_t)Nn * 4, stream);

    // fused setup: weight prep, x convert, degree count
    setup_kernel<<<2048, 256, 0, stream>>>(
        Wl1, Wr1, wt1h, Wl2, Wr2, wt2h,
        Wl3, Wr3, b3, Wout, bout, Wc, bc,
        x, xb, dst, cnt, Nn, E);

    const int nb = (Nn + 1 + 4095) / 4096;   // 13
    scan_local_kernel<<<nb, 1024, 0, stream>>>(cnt, row_ptr, bsums, Nn);
    scan_add_kernel<<<nb, 1024, 0, stream>>>(row_ptr, bsums, Nn);
    scatter_kernel<<<2048, 256, 0, stream>>>(src, dst, row_ptr, cursor, esrc, E);

    const int gm32 = (Nn + 31) / 32;    // 1563

    // Layer 1: [agg1 | x] -> 256, relu; bf16 out
    aggregate_bf16_kernel<128><<<2048, 256, 0, stream>>>(xb, row_ptr, esrc, agg1b, Nn);
    gemm_lds_kernel<128, 128, 256, true, false>
        <<<gm32, 256, 0, stream>>>(agg1b, xb, (const short8x*)wt1h,
                                   b1, h1b, nullptr, nullptr, nullptr, Nn);

    // Layer 2: [agg2 | h1] -> 256, relu; fused tu epilogue (no h2 materialized)
    aggregate_bf16_kernel<256><<<2048, 256, 0, stream>>>(h1b, row_ptr, esrc, agg2b, Nn);
    gemm_lds_kernel<256, 256, 256, true, true>
        <<<gm32, 256, 0, stream>>>(agg2b, h1b, (const short8x*)wt2h,
                                   b2, nullptr, Wc, bc, tu, Nn);

    // out = mean-gather(t) + u
    final_out_kernel<<<512, 256, 0, stream>>>(tu, row_ptr, esrc, (float*)d_out, Nn);
}